// Round 13
// baseline (859.622 us; speedup 1.0000x reference)
//
#include <hip/hip_runtime.h>

// Problem constants (from reference)
#define N_C 50000
#define N_V 100000
#define N_A 5000
#define E_C2V 1600000
#define E_A2V 1000000
#define D_V 13
#define D_C 14
#define D_A 14
#define EMB 32

// Residue-major node-index permutation (XCD-local CSR/perm lines; round 8).
#define PV(t) (((t) >> 3) + ((t)&7) * (N_V / 8))  // N_V/8 = 12500
#define PA(t) (((t) >> 3) + ((t)&7) * (N_A / 8))  // N_A/8 = 625
#define NCH (E_C2V / 256)                         // 6250 chunks, exact

typedef float v2f __attribute__((ext_vector_type(2)));

// h2[j] (16 x float2 = 32 channels) += v * Wrow[2j..2j+1] via v_pk_fma_f32.
__device__ __forceinline__ void accrow2(v2f* __restrict__ h, float v,
                                        const float* __restrict__ Wrow) {
  const v2f* w = (const v2f*)Wrow;
  v2f vv = {v, v};
#pragma unroll
  for (int j = 0; j < 16; ++j) h[j] = __builtin_elementwise_fma(vv, w[j], h[j]);
}

__device__ __forceinline__ void relu2(v2f* __restrict__ h) {
  v2f z = {0.0f, 0.0f};
#pragma unroll
  for (int j = 0; j < 16; ++j) h[j] = __builtin_elementwise_max(h[j], z);
}

__device__ __forceinline__ void layer2(v2f* __restrict__ o2,
                                       const v2f* __restrict__ h,
                                       const float* __restrict__ W2,
                                       const float* __restrict__ b2) {
  const v2f* b = (const v2f*)b2;
#pragma unroll
  for (int j = 0; j < 16; ++j) o2[j] = b[j];
#pragma unroll
  for (int k = 0; k < EMB; ++k) {
    float hk = h[k >> 1][k & 1];
    accrow2(o2, hk, W2 + k * EMB);
  }
}

// Register-level segmented reduce over the wave + flush to hacc.
// acc[16] = this lane's post-relu 32-vec; key = this lane's node id.
// PIDX: 0 -> PV, 1 -> PA.  ADDMODE: interior rows load+add (h pass).
template <int ADDMODE, int PIDX>
__device__ __forceinline__ void seg_reduce_flush(
    v2f* __restrict__ acc, int key, int lane,
    const float* __restrict__ Wp, const int* __restrict__ deg,
    float* __restrict__ hacc) {
  int nprev = __shfl_up(key, 1, 64);
  int nnext = __shfl_down(key, 1, 64);
  bool head = (lane == 0) || (key != nprev);
  bool tail = (lane == 63) || (key != nnext);
  // segment-start index via max-scan of head positions
  int s = head ? lane : 0;
#pragma unroll
  for (int d = 1; d < 64; d <<= 1) {
    int o = __shfl_up(s, d, 64);
    if (lane >= d && o > s) s = o;
  }
  // segmented inclusive sum-scan of acc across lanes
#pragma unroll
  for (int d = 1; d < 64; d <<= 1) {
    bool take = (lane >= d) && ((lane - d) >= s);
#pragma unroll
    for (int j = 0; j < 16; ++j) {
      float ax = __shfl_up(acc[j].x, d, 64);
      float ay = __shfl_up(acc[j].y, d, 64);
      if (take) {
        acc[j].x += ax;
        acc[j].y += ay;
      }
    }
  }
  // flush each segment (tail lanes hold full segment sums)
  unsigned long long tmask = __ballot(tail);
  while (tmask) {
    int r = (int)(__ffsll((unsigned long long)tmask) - 1);
    tmask &= tmask - 1;
    int cur = __shfl(key, r, 64);
    int sr = __shfl(s, r, 64);
    float seg[EMB];
#pragma unroll
    for (int j = 0; j < 16; ++j) {
      seg[2 * j] = __shfl(acc[j].x, r, 64);
      seg[2 * j + 1] = __shfl(acc[j].y, r, 64);
    }
    int p = PIDX ? PA(cur) : PV(cur);
    float inv = 1.0f / fmaxf((float)deg[p], 1.0f);
    if (lane < EMB) {
      float out = 0.0f;
#pragma unroll
      for (int k = 0; k < EMB; ++k)
        out = fmaf(seg[k], Wp[k * EMB + lane], out);
      out *= inv;  // mean-scale folded after the linear projection
      float* dst = &hacc[(size_t)cur * EMB + lane];
      bool interior = (sr > 0) && (r < 63);  // node's full range in-window
      if (interior) {
        if (ADDMODE) out += *dst;
        *dst = out;
      } else {
        atomicAdd(dst, out);
      }
    }
  }
}

// -------- degree histograms + per-edge rank capture (atomicAdd return).
__global__ __launch_bounds__(256) void k_counts(
    const int* __restrict__ c2v_t, const int* __restrict__ a2v_t,
    const int* __restrict__ a2v_s, int* __restrict__ deg_g,
    int* __restrict__ deg_h, int* __restrict__ deg_a,
    unsigned short* __restrict__ rank_g, unsigned short* __restrict__ rank_h,
    unsigned short* __restrict__ rank_a) {
  int e = blockIdx.x * 256 + threadIdx.x;  // grid exact: E_C2V % 256 == 0
  int t = c2v_t[e];
  rank_g[e] = (unsigned short)atomicAdd(&deg_g[PV(t)], 1);
  if (e < E_A2V) {
    int th = a2v_t[e];
    rank_h[e] = (unsigned short)atomicAdd(&deg_h[PV(th)], 1);
    int ta = a2v_s[e];
    rank_a[e] = (unsigned short)atomicAdd(&deg_a[PA(ta)], 1);
  }
}

// -------- merged slot allocation (order-agnostic disjoint ranges)
#define NBV ((N_V + 255) / 256)  // 391
#define NBA ((N_A + 255) / 256)  // 20
__global__ __launch_bounds__(256) void k_allocs(
    const int* __restrict__ deg_g, int* __restrict__ off_g,
    const int* __restrict__ deg_h, int* __restrict__ off_h,
    const int* __restrict__ deg_a, int* __restrict__ off_a,
    int* __restrict__ ctr) {
  const int* deg;
  int* off;
  int* c;
  int i, n;
  if (blockIdx.x < NBV) {
    i = blockIdx.x * 256 + threadIdx.x;
    deg = deg_g; off = off_g; c = ctr + 0; n = N_V;
  } else if (blockIdx.x < 2 * NBV) {
    i = (blockIdx.x - NBV) * 256 + threadIdx.x;
    deg = deg_h; off = off_h; c = ctr + 1; n = N_V;
  } else {
    i = (blockIdx.x - 2 * NBV) * 256 + threadIdx.x;
    deg = deg_a; off = off_a; c = ctr + 2; n = N_A;
  }
  int lane = threadIdx.x & 63;
  int d = (i < n) ? deg[i] : 0;
  int v = d;
#pragma unroll
  for (int s = 1; s < 64; s <<= 1) {
    int t = __shfl_up(v, s, 64);
    if (lane >= s) v += t;
  }
  int total = __shfl(v, 63, 64);
  int base = 0;
  if (lane == 63) base = atomicAdd(c, total);
  base = __shfl(base, 63, 64);
  if (i < n) off[i] = base + v - d;
}

// -------- ATOMIC-FREE CSR fill: pos = off[key] + rank[e]. Residue-partitioned
// (8 blocks per 256-edge chunk) so scatter lines stay XCD-local (round 8).
__global__ __launch_bounds__(256) void k_fill(
    const int* __restrict__ c2v_t, const int* __restrict__ off_g,
    const unsigned short* __restrict__ rank_g, int* __restrict__ perm_g,
    const int* __restrict__ a2v_t, const int* __restrict__ off_h,
    const unsigned short* __restrict__ rank_h, int* __restrict__ perm_h,
    const int* __restrict__ a2v_s, const int* __restrict__ off_a,
    const unsigned short* __restrict__ rank_a, int* __restrict__ perm_a) {
  int res = blockIdx.x & 7;
  int e = (blockIdx.x >> 3) * 256 + threadIdx.x;
  int t = c2v_t[e];
  if ((t & 7) == res) perm_g[off_g[PV(t)] + rank_g[e]] = e;
  if (e < E_A2V) {
    int th = a2v_t[e];
    if ((th & 7) == res) perm_h[off_h[PV(th)] + rank_h[e]] = e;
    int ta = a2v_s[e];
    if ((ta & 7) == res) perm_a[off_a[PA(ta)] + rank_a[e]] = e;
  }
}

// -------- edge-parallel v-side edge MLP (FIN=28, packed) + register-level
// segmented reduce (shuffles, zero LDS) + projection -> hacc.
template <int ADDMODE>
__global__ __launch_bounds__(256, 5) void k_edge_v(
    int E,
    const int* __restrict__ perm, const int* __restrict__ tgt,
    const int* __restrict__ srcv,
    const float* __restrict__ x_t,   // variable-node feats (13)
    const float* __restrict__ x_s,   // source feats (14), rows 8B-aligned
    const float* __restrict__ ea,
    const float* __restrict__ W1, const float* __restrict__ b1,
    const float* __restrict__ W2, const float* __restrict__ b2,
    const float* __restrict__ Wp,    // fW1 + (13 or 45)*32 projection slice
    const int* __restrict__ deg,     // residue-major indexed
    float* __restrict__ hacc) {
  int lane = threadIdx.x & 63;
  int slot = blockIdx.x * 256 + threadIdx.x;
  if ((slot & ~63) >= E) return;  // wave-uniform exit (E % 64 == 0)

  int e = perm[slot];
  int t = tgt[e];
  float eav = ea[e];
  int s = srcv[e];
  const float* xt = x_t + (size_t)t * D_V;

  v2f h[16];
  const v2f* b1v = (const v2f*)b1;
#pragma unroll
  for (int j = 0; j < 16; ++j) h[j] = b1v[j];
#pragma unroll
  for (int i = 0; i < D_V; ++i) accrow2(h, xt[i], W1 + i * EMB);
  const float2* xs2 = (const float2*)(x_s + (size_t)s * D_C);
#pragma unroll
  for (int i = 0; i < 7; ++i) {
    float2 wv2 = xs2[i];
    accrow2(h, wv2.x, W1 + (D_V + 2 * i) * EMB);
    accrow2(h, wv2.y, W1 + (D_V + 2 * i + 1) * EMB);
  }
  accrow2(h, eav, W1 + 27 * EMB);
  relu2(h);
  v2f o2[16];
  layer2(o2, h, W2, b2);
  relu2(o2);
  seg_reduce_flush<ADDMODE, 0>(o2, t, lane, Wp, deg, hacc);
}

// -------- edge-parallel a-side g_a MLP (FIN=47, packed) + register reduce
__global__ __launch_bounds__(256, 5) void k_edge_a(
    const int* __restrict__ perm,
    const int* __restrict__ a2v_s, const int* __restrict__ a2v_t,
    const float* __restrict__ xa_g, const float* __restrict__ fv,
    const float* __restrict__ ea,
    const float* __restrict__ W1, const float* __restrict__ b1,
    const float* __restrict__ W2, const float* __restrict__ b2,
    const float* __restrict__ Wp,   // fa_W1 + 14*32
    const int* __restrict__ deg,
    float* __restrict__ hacc_a) {
  int lane = threadIdx.x & 63;
  int slot = blockIdx.x * 256 + threadIdx.x;
  if ((slot & ~63) >= E_A2V) return;

  int e = perm[slot];
  int a = a2v_s[e];
  int t = a2v_t[e];
  float eav = ea[e];

  v2f h[16];
  const v2f* b1v = (const v2f*)b1;
#pragma unroll
  for (int j = 0; j < 16; ++j) h[j] = b1v[j];
  const float2* ps2 = (const float2*)(xa_g + (size_t)a * D_A);
#pragma unroll
  for (int i = 0; i < 7; ++i) {
    float2 wv2 = ps2[i];
    accrow2(h, wv2.x, W1 + (2 * i) * EMB);
    accrow2(h, wv2.y, W1 + (2 * i + 1) * EMB);
  }
  const float4* pf = (const float4*)(fv + (size_t)t * EMB);
#pragma unroll
  for (int q = 0; q < 8; ++q) {
    float4 f = pf[q];
    accrow2(h, f.x, W1 + (D_A + 4 * q) * EMB);
    accrow2(h, f.y, W1 + (D_A + 4 * q + 1) * EMB);
    accrow2(h, f.z, W1 + (D_A + 4 * q + 2) * EMB);
    accrow2(h, f.w, W1 + (D_A + 4 * q + 3) * EMB);
  }
  accrow2(h, eav, W1 + 46 * EMB);
  relu2(h);
  v2f o2[16];
  layer2(o2, h, W2, b2);
  relu2(o2);
  seg_reduce_flush<0, 1>(o2, a, lane, Wp, deg, hacc_a);
}

// -------- f_v node MLP on pre-accumulated hidden (packed)
__global__ __launch_bounds__(256) void k_node_fv(
    const float* __restrict__ xv_g, const float* __restrict__ hacc,
    const float* __restrict__ fW1, const float* __restrict__ fb1,
    const float* __restrict__ fW2, const float* __restrict__ fb2,
    float* __restrict__ fv_out) {
  int v = blockIdx.x * blockDim.x + threadIdx.x;
  if (v >= N_V) return;
  const v2f* hr = (const v2f*)(hacc + (size_t)v * EMB);
  const v2f* bv = (const v2f*)fb1;
  v2f h[16];
#pragma unroll
  for (int j = 0; j < 16; ++j) h[j] = bv[j] + hr[j];
  const float* pv = xv_g + (size_t)v * D_V;
#pragma unroll
  for (int i = 0; i < D_V; ++i) accrow2(h, pv[i], fW1 + i * EMB);
  relu2(h);
  v2f o2[16];
  layer2(o2, h, fW2, fb2);
  v2f z = {0.0f, 0.0f};
  v2f* dst = (v2f*)(fv_out + (size_t)v * EMB);
#pragma unroll
  for (int j = 0; j < 16; ++j)
    dst[j] = __builtin_elementwise_max(o2[j], z);
}

// -------- f_a node MLP on pre-accumulated hidden -> d_out (packed)
__global__ __launch_bounds__(256) void k_node_fa(
    const float* __restrict__ xa, const float* __restrict__ hacc_a,
    const float* __restrict__ W1, const float* __restrict__ b1,
    const float* __restrict__ W2, const float* __restrict__ b2,
    float* __restrict__ out) {
  int a = blockIdx.x * blockDim.x + threadIdx.x;
  if (a >= N_A) return;
  const v2f* hr = (const v2f*)(hacc_a + (size_t)a * EMB);
  const v2f* bv = (const v2f*)b1;
  v2f h[16];
#pragma unroll
  for (int j = 0; j < 16; ++j) h[j] = bv[j] + hr[j];
  const float2* pa = (const float2*)(xa + (size_t)a * D_A);
#pragma unroll
  for (int i = 0; i < 7; ++i) {
    float2 w = pa[i];
    accrow2(h, w.x, W1 + (2 * i) * EMB);
    accrow2(h, w.y, W1 + (2 * i + 1) * EMB);
  }
  relu2(h);
  v2f o2[16];
  layer2(o2, h, W2, b2);
  v2f z = {0.0f, 0.0f};
  v2f* dst = (v2f*)(out + (size_t)a * EMB);
#pragma unroll
  for (int j = 0; j < 16; ++j)
    dst[j] = __builtin_elementwise_max(o2[j], z);
}

extern "C" void kernel_launch(void* const* d_in, const int* in_sizes, int n_in,
                              void* d_out, int out_size, void* d_ws, size_t ws_size,
                              hipStream_t stream) {
  const float* x_c = (const float*)d_in[0];
  const float* x_v = (const float*)d_in[1];
  const float* x_a = (const float*)d_in[2];
  const int* c2v_s = (const int*)d_in[3];
  const int* c2v_t = (const int*)d_in[4];
  const int* a2v_s = (const int*)d_in[5];
  const int* a2v_t = (const int*)d_in[6];
  const float* ea_c2v = (const float*)d_in[7];
  const float* ea_a2v = (const float*)d_in[8];
  const float* gv_W1 = (const float*)d_in[9];
  const float* gv_b1 = (const float*)d_in[10];
  const float* gv_W2 = (const float*)d_in[11];
  const float* gv_b2 = (const float*)d_in[12];
  const float* hv_W1 = (const float*)d_in[13];
  const float* hv_b1 = (const float*)d_in[14];
  const float* hv_W2 = (const float*)d_in[15];
  const float* hv_b2 = (const float*)d_in[16];
  const float* fv_W1 = (const float*)d_in[17];
  const float* fv_b1 = (const float*)d_in[18];
  const float* fv_W2 = (const float*)d_in[19];
  const float* fv_b2 = (const float*)d_in[20];
  const float* ga_W1 = (const float*)d_in[21];
  const float* ga_b1 = (const float*)d_in[22];
  const float* ga_W2 = (const float*)d_in[23];
  const float* ga_b2 = (const float*)d_in[24];
  const float* fa_W1 = (const float*)d_in[25];
  const float* fa_b1 = (const float*)d_in[26];
  const float* fa_W2 = (const float*)d_in[27];
  const float* fa_b2 = (const float*)d_in[28];

  // ---- workspace layout: ~39.5 MB (proven envelope ~39.9 MB) ----
  int* ip = (int*)d_ws;
  int* deg_g = ip;                  // 100000
  int* deg_h = deg_g + N_V;         // 100000
  int* deg_a = deg_h + N_V;         // 5000
  int* ctr = deg_a + N_A;           // 4
  float* hacc = (float*)(ctr + 4);              // N_V*32
  float* hacc_a = hacc + (size_t)N_V * EMB;     // N_A*32
  int* off_g = (int*)(hacc_a + (size_t)N_A * EMB);  // 100000
  int* off_h = off_g + N_V;                         // 100000
  int* off_a = off_h + N_V;                         // 5000
  // Region B: 3.2M ints, time-multiplexed:
  //   phase 1: perm_g(1.6M)+perm_h(1.0M)  [fill .. edge_h]
  //   phase 2: fv (3.2M floats)           [node_fv .. edge_a]
  int* B = off_a + N_A;
  int* perm_g = B;
  int* perm_h = B + E_C2V;
  float* fv = (float*)B;
  int* perm_a = B + 2 * E_C2V;
  unsigned short* rank_g = (unsigned short*)(perm_a + E_A2V);  // 1.6M
  unsigned short* rank_h = rank_g + E_C2V;                     // 1.0M
  unsigned short* rank_a = rank_h + E_A2V;                     // 1.0M

  hipMemsetAsync(d_ws, 0,
                 (size_t)305004 * sizeof(int) +
                     (size_t)(N_V + N_A) * EMB * sizeof(float),
                 stream);

  // degrees + ranks (single pass, 1 thread/edge)
  k_counts<<<NCH, 256, 0, stream>>>(c2v_t, a2v_t, a2v_s, deg_g, deg_h, deg_a,
                                    rank_g, rank_h, rank_a);
  k_allocs<<<2 * NBV + NBA, 256, 0, stream>>>(deg_g, off_g, deg_h, off_h,
                                              deg_a, off_a, ctr);
  // atomic-free fill (residue-partitioned scatter)
  k_fill<<<8 * NCH, 256, 0, stream>>>(
      c2v_t, off_g, rank_g, perm_g, a2v_t, off_h, rank_h, perm_h,
      a2v_s, off_a, rank_a, perm_a);
  // g side edge MLP + reduce -> hacc
  k_edge_v<0><<<E_C2V / 256, 256, 0, stream>>>(
      E_C2V, perm_g, c2v_t, c2v_s, x_v, x_c, ea_c2v,
      gv_W1, gv_b1, gv_W2, gv_b2, fv_W1 + (size_t)D_V * EMB, deg_g, hacc);
  // h side edge MLP + reduce -> hacc
  k_edge_v<1><<<(E_A2V + 255) / 256, 256, 0, stream>>>(
      E_A2V, perm_h, a2v_t, a2v_s, x_v, x_a, ea_a2v,
      hv_W1, hv_b1, hv_W2, hv_b2, fv_W1 + (size_t)(D_V + EMB) * EMB, deg_h,
      hacc);
  // f_v from hacc; fv lands in B (perm_g/perm_h dead)
  k_node_fv<<<(N_V + 255) / 256, 256, 0, stream>>>(
      x_v, hacc, fv_W1, fv_b1, fv_W2, fv_b2, fv);
  // a side edge MLP + reduce -> hacc_a
  k_edge_a<<<(E_A2V + 255) / 256, 256, 0, stream>>>(
      perm_a, a2v_s, a2v_t, x_a, fv, ea_a2v,
      ga_W1, ga_b1, ga_W2, ga_b2, fa_W1 + (size_t)D_A * EMB, deg_a, hacc_a);
  // f_a -> out
  k_node_fa<<<(N_A + 255) / 256, 256, 0, stream>>>(
      x_a, hacc_a, fa_W1, fa_b1, fa_W2, fa_b2, (float*)d_out);
}

// Round 14
// 768.922 us; speedup vs baseline: 1.1180x; 1.1180x over previous
//
#include <hip/hip_runtime.h>

// Problem constants (from reference)
#define N_C 50000
#define N_V 100000
#define N_A 5000
#define E_C2V 1600000
#define E_A2V 1000000
#define D_V 13
#define D_C 14
#define D_A 14
#define EMB 32

// Residue-major node-index permutation (XCD-local CSR lines; round 8).
#define PV(t) (((t) >> 3) + ((t)&7) * (N_V / 8))  // N_V/8 = 12500
#define PA(t) (((t) >> 3) + ((t)&7) * (N_A / 8))  // N_A/8 = 625
#define NCH (E_C2V / 256)                         // 6250 chunks, exact
#define NCHA ((E_A2V + 255) / 256)                // 3907

typedef float v2f __attribute__((ext_vector_type(2)));

// h2[j] (16 x float2 = 32 channels) += v * Wrow[2j..2j+1] via v_pk_fma_f32.
__device__ __forceinline__ void accrow2(v2f* __restrict__ h, float v,
                                        const float* __restrict__ Wrow) {
  const v2f* w = (const v2f*)Wrow;
  v2f vv = {v, v};
#pragma unroll
  for (int j = 0; j < 16; ++j) h[j] = __builtin_elementwise_fma(vv, w[j], h[j]);
}

__device__ __forceinline__ void relu2(v2f* __restrict__ h) {
  v2f z = {0.0f, 0.0f};
#pragma unroll
  for (int j = 0; j < 16; ++j) h[j] = __builtin_elementwise_max(h[j], z);
}

__device__ __forceinline__ void layer2(v2f* __restrict__ o2,
                                       const v2f* __restrict__ h,
                                       const float* __restrict__ W2,
                                       const float* __restrict__ b2) {
  const v2f* b = (const v2f*)b2;
#pragma unroll
  for (int j = 0; j < 16; ++j) o2[j] = b[j];
#pragma unroll
  for (int k = 0; k < EMB; ++k) {
    float hk = h[k >> 1][k & 1];
    accrow2(o2, hk, W2 + k * EMB);
  }
}

// -------- degree histograms + per-edge rank capture (atomicAdd return).
__global__ __launch_bounds__(256) void k_counts(
    const int* __restrict__ c2v_t, const int* __restrict__ a2v_t,
    const int* __restrict__ a2v_s, int* __restrict__ deg_g,
    int* __restrict__ deg_h, int* __restrict__ deg_a,
    unsigned short* __restrict__ rank_g, unsigned short* __restrict__ rank_h,
    unsigned short* __restrict__ rank_a) {
  int e = blockIdx.x * 256 + threadIdx.x;  // grid exact: E_C2V % 256 == 0
  int t = c2v_t[e];
  rank_g[e] = (unsigned short)atomicAdd(&deg_g[PV(t)], 1);
  if (e < E_A2V) {
    int th = a2v_t[e];
    rank_h[e] = (unsigned short)atomicAdd(&deg_h[PV(th)], 1);
    int ta = a2v_s[e];
    rank_a[e] = (unsigned short)atomicAdd(&deg_a[PA(ta)], 1);
  }
}

// -------- merged slot allocation (order-agnostic disjoint ranges)
#define NBV ((N_V + 255) / 256)  // 391
#define NBA ((N_A + 255) / 256)  // 20
__global__ __launch_bounds__(256) void k_allocs(
    const int* __restrict__ deg_g, int* __restrict__ off_g,
    const int* __restrict__ deg_h, int* __restrict__ off_h,
    const int* __restrict__ deg_a, int* __restrict__ off_a,
    int* __restrict__ ctr) {
  const int* deg;
  int* off;
  int* c;
  int i, n;
  if (blockIdx.x < NBV) {
    i = blockIdx.x * 256 + threadIdx.x;
    deg = deg_g; off = off_g; c = ctr + 0; n = N_V;
  } else if (blockIdx.x < 2 * NBV) {
    i = (blockIdx.x - NBV) * 256 + threadIdx.x;
    deg = deg_h; off = off_h; c = ctr + 1; n = N_V;
  } else {
    i = (blockIdx.x - 2 * NBV) * 256 + threadIdx.x;
    deg = deg_a; off = off_a; c = ctr + 2; n = N_A;
  }
  int lane = threadIdx.x & 63;
  int d = (i < n) ? deg[i] : 0;
  int v = d;
#pragma unroll
  for (int s = 1; s < 64; s <<= 1) {
    int t = __shfl_up(v, s, 64);
    if (lane >= s) v += t;
  }
  int total = __shfl(v, 63, 64);
  int base = 0;
  if (lane == 63) base = atomicAdd(c, total);
  base = __shfl(base, 63, 64);
  if (i < n) off[i] = base + v - d;
}

// -------- atomic-free payload fills: materialize (t, s, ea) in CSR order.
// pos = off[key] + rank[e]; residue-partitioned so scatter lines stay
// XCD-local. Kills the e-indexed random gathers in the edge kernels
// (round-13 counters: 341 MB FETCH in edge_g, ~3x 64B-line amplification).
__global__ __launch_bounds__(256) void k_fill_g(
    const int* __restrict__ c2v_t, const int* __restrict__ c2v_s,
    const float* __restrict__ ea, const int* __restrict__ off_g,
    const unsigned short* __restrict__ rank_g,
    int* __restrict__ t_g, unsigned short* __restrict__ s_g,
    float* __restrict__ ea_g) {
  int res = blockIdx.x & 7;
  int e = (blockIdx.x >> 3) * 256 + threadIdx.x;  // 8*NCH grid, exact
  int t = c2v_t[e];
  if ((t & 7) == res) {
    int pos = off_g[PV(t)] + rank_g[e];
    t_g[pos] = t;
    s_g[pos] = (unsigned short)c2v_s[e];  // N_C = 50000 < 65536
    ea_g[pos] = ea[e];
  }
}

__global__ __launch_bounds__(256) void k_fill_h(
    const int* __restrict__ a2v_t, const int* __restrict__ a2v_s,
    const float* __restrict__ ea, const int* __restrict__ off_h,
    const unsigned short* __restrict__ rank_h,
    int* __restrict__ t_h, unsigned short* __restrict__ s_h,
    float* __restrict__ ea_h) {
  int res = blockIdx.x & 7;
  int e = (blockIdx.x >> 3) * 256 + threadIdx.x;
  if (e >= E_A2V) return;
  int t = a2v_t[e];
  if ((t & 7) == res) {
    int pos = off_h[PV(t)] + rank_h[e];
    t_h[pos] = t;
    s_h[pos] = (unsigned short)a2v_s[e];  // N_A = 5000
    ea_h[pos] = ea[e];
  }
}

__global__ __launch_bounds__(256) void k_fill_a(
    const int* __restrict__ a2v_s, const int* __restrict__ a2v_t,
    const float* __restrict__ ea, const int* __restrict__ off_a,
    const unsigned short* __restrict__ rank_a,
    unsigned short* __restrict__ key_a, int* __restrict__ t_a,
    float* __restrict__ ea_a) {
  int res = blockIdx.x & 7;
  int e = (blockIdx.x >> 3) * 256 + threadIdx.x;
  if (e >= E_A2V) return;
  int a = a2v_s[e];
  if ((a & 7) == res) {
    int pos = off_a[PA(a)] + rank_a[e];
    key_a[pos] = (unsigned short)a;
    t_a[pos] = a2v_t[e];
    ea_a[pos] = ea[e];
  }
}

// -------- edge-parallel v-side edge MLP (FIN=28, packed) + per-wave LDS
// segmented reduce + projection through the f_v W1 slice -> hacc.
// All per-edge inputs are coalesced CSR-order payload arrays (no gathers
// except the x_t/x_s feature rows, which are small and L2-resident).
template <int ADDMODE>
__global__ __launch_bounds__(256) void k_edge_v(
    int E,
    const int* __restrict__ t_arr, const unsigned short* __restrict__ s_arr,
    const float* __restrict__ ea_arr,
    const float* __restrict__ x_t,   // variable-node feats (13)
    const float* __restrict__ x_s,   // source feats (14), rows 8B-aligned
    const float* __restrict__ W1, const float* __restrict__ b1,
    const float* __restrict__ W2, const float* __restrict__ b2,
    const float* __restrict__ Wp,    // fW1 + (13 or 45)*32 projection slice
    const int* __restrict__ deg,     // residue-major indexed
    float* __restrict__ hacc) {
  __shared__ float vals[4][64][34];
  __shared__ int nidl[4][64];
  __shared__ float segx[4][32];
  int wv = threadIdx.x >> 6;
  int lane = threadIdx.x & 63;
  int slot = blockIdx.x * 256 + threadIdx.x;
  if ((slot & ~63) >= E) return;  // wave-uniform exit (E % 64 == 0)

  int t = t_arr[slot];
  int s = (int)s_arr[slot];
  float eav = ea_arr[slot];
  const float* xt = x_t + (size_t)t * D_V;

  v2f h[16];
  const v2f* b1v = (const v2f*)b1;
#pragma unroll
  for (int j = 0; j < 16; ++j) h[j] = b1v[j];
#pragma unroll
  for (int i = 0; i < D_V; ++i) accrow2(h, xt[i], W1 + i * EMB);
  const float2* xs2 = (const float2*)(x_s + (size_t)s * D_C);
#pragma unroll
  for (int i = 0; i < 7; ++i) {
    float2 wv2 = xs2[i];
    accrow2(h, wv2.x, W1 + (D_V + 2 * i) * EMB);
    accrow2(h, wv2.y, W1 + (D_V + 2 * i + 1) * EMB);
  }
  accrow2(h, eav, W1 + 27 * EMB);
  relu2(h);
  v2f o2[16];
  layer2(o2, h, W2, b2);
  {
    v2f z = {0.0f, 0.0f};
    v2f* vr = (v2f*)&vals[wv][lane][0];
#pragma unroll
    for (int j = 0; j < 16; ++j) vr[j] = __builtin_elementwise_max(o2[j], z);
  }
  nidl[wv][lane] = t;
  // wave-synchronous segmented reduce (32 channel-lanes)
  if (lane < EMB) {
    int j = lane;
    float acc = 0.0f;
    int r0 = 0;
    for (int r = 0; r < 64; ++r) {
      acc += vals[wv][r][j];
      int cur = nidl[wv][r];
      bool flush = (r == 63) || (nidl[wv][r + 1] != cur);
      if (flush) {  // wave-uniform
        float inv = 1.0f / fmaxf((float)deg[PV(cur)], 1.0f);
        segx[wv][j] = acc * inv;
        float out = 0.0f;
#pragma unroll
        for (int k = 0; k < EMB; ++k)
          out = fmaf(segx[wv][k], Wp[k * EMB + j], out);
        float* dst = &hacc[(size_t)cur * EMB + j];
        if (r0 > 0 && r < 63) {  // interior: sole writer for this row
          if (ADDMODE) out += *dst;
          *dst = out;
        } else {
          atomicAdd(dst, out);
        }
        acc = 0.0f;
        r0 = r + 1;
      }
    }
  }
}

// -------- edge-parallel a-side g_a MLP (FIN=47, packed) + reduce -> hacc_a
__global__ __launch_bounds__(256) void k_edge_a(
    const unsigned short* __restrict__ key_a, const int* __restrict__ t_a,
    const float* __restrict__ ea_arr,
    const float* __restrict__ xa_g, const float* __restrict__ fv,
    const float* __restrict__ W1, const float* __restrict__ b1,
    const float* __restrict__ W2, const float* __restrict__ b2,
    const float* __restrict__ Wp,   // fa_W1 + 14*32
    const int* __restrict__ deg,
    float* __restrict__ hacc_a) {
  __shared__ float vals[4][64][34];
  __shared__ int nidl[4][64];
  __shared__ float segx[4][32];
  int wv = threadIdx.x >> 6;
  int lane = threadIdx.x & 63;
  int slot = blockIdx.x * 256 + threadIdx.x;
  if ((slot & ~63) >= E_A2V) return;

  int a = (int)key_a[slot];
  int t = t_a[slot];
  float eav = ea_arr[slot];

  v2f h[16];
  const v2f* b1v = (const v2f*)b1;
#pragma unroll
  for (int j = 0; j < 16; ++j) h[j] = b1v[j];
  const float2* ps2 = (const float2*)(xa_g + (size_t)a * D_A);
#pragma unroll
  for (int i = 0; i < 7; ++i) {
    float2 wv2 = ps2[i];
    accrow2(h, wv2.x, W1 + (2 * i) * EMB);
    accrow2(h, wv2.y, W1 + (2 * i + 1) * EMB);
  }
  const float4* pf = (const float4*)(fv + (size_t)t * EMB);
#pragma unroll
  for (int q = 0; q < 8; ++q) {
    float4 f = pf[q];
    accrow2(h, f.x, W1 + (D_A + 4 * q) * EMB);
    accrow2(h, f.y, W1 + (D_A + 4 * q + 1) * EMB);
    accrow2(h, f.z, W1 + (D_A + 4 * q + 2) * EMB);
    accrow2(h, f.w, W1 + (D_A + 4 * q + 3) * EMB);
  }
  accrow2(h, eav, W1 + 46 * EMB);
  relu2(h);
  v2f o2[16];
  layer2(o2, h, W2, b2);
  {
    v2f z = {0.0f, 0.0f};
    v2f* vr = (v2f*)&vals[wv][lane][0];
#pragma unroll
    for (int j = 0; j < 16; ++j) vr[j] = __builtin_elementwise_max(o2[j], z);
  }
  nidl[wv][lane] = a;
  if (lane < EMB) {
    int j = lane;
    float acc = 0.0f;
    int r0 = 0;
    for (int r = 0; r < 64; ++r) {
      acc += vals[wv][r][j];
      int cur = nidl[wv][r];
      bool flush = (r == 63) || (nidl[wv][r + 1] != cur);
      if (flush) {
        float inv = 1.0f / fmaxf((float)deg[PA(cur)], 1.0f);
        segx[wv][j] = acc * inv;
        float out = 0.0f;
#pragma unroll
        for (int k = 0; k < EMB; ++k)
          out = fmaf(segx[wv][k], Wp[k * EMB + j], out);
        float* dst = &hacc_a[(size_t)cur * EMB + j];
        if (r0 > 0 && r < 63) {
          *dst = out;  // sole writer (zeroed buffer, single dispatch)
        } else {
          atomicAdd(dst, out);
        }
        acc = 0.0f;
        r0 = r + 1;
      }
    }
  }
}

// -------- f_v node MLP, IN-PLACE on hacc (row v read then overwritten by
// the same thread -> safe; saves the separate 12.8 MB fv buffer).
__global__ __launch_bounds__(256) void k_node_fv(
    const float* __restrict__ xv_g, float* hf,
    const float* __restrict__ fW1, const float* __restrict__ fb1,
    const float* __restrict__ fW2, const float* __restrict__ fb2) {
  int v = blockIdx.x * blockDim.x + threadIdx.x;
  if (v >= N_V) return;
  v2f* row = (v2f*)(hf + (size_t)v * EMB);
  const v2f* bv = (const v2f*)fb1;
  v2f h[16];
#pragma unroll
  for (int j = 0; j < 16; ++j) h[j] = bv[j] + row[j];
  const float* pv = xv_g + (size_t)v * D_V;
#pragma unroll
  for (int i = 0; i < D_V; ++i) accrow2(h, pv[i], fW1 + i * EMB);
  relu2(h);
  v2f o2[16];
  layer2(o2, h, fW2, fb2);
  v2f z = {0.0f, 0.0f};
#pragma unroll
  for (int j = 0; j < 16; ++j)
    row[j] = __builtin_elementwise_max(o2[j], z);  // relu_out (+idempotent)
}

// -------- f_a node MLP on pre-accumulated hidden -> d_out (packed)
__global__ __launch_bounds__(256) void k_node_fa(
    const float* __restrict__ xa, const float* __restrict__ hacc_a,
    const float* __restrict__ W1, const float* __restrict__ b1,
    const float* __restrict__ W2, const float* __restrict__ b2,
    float* __restrict__ out) {
  int a = blockIdx.x * blockDim.x + threadIdx.x;
  if (a >= N_A) return;
  const v2f* hr = (const v2f*)(hacc_a + (size_t)a * EMB);
  const v2f* bv = (const v2f*)b1;
  v2f h[16];
#pragma unroll
  for (int j = 0; j < 16; ++j) h[j] = bv[j] + hr[j];
  const float2* pa = (const float2*)(xa + (size_t)a * D_A);
#pragma unroll
  for (int i = 0; i < 7; ++i) {
    float2 w = pa[i];
    accrow2(h, w.x, W1 + (2 * i) * EMB);
    accrow2(h, w.y, W1 + (2 * i + 1) * EMB);
  }
  relu2(h);
  v2f o2[16];
  layer2(o2, h, W2, b2);
  v2f z = {0.0f, 0.0f};
  v2f* dst = (v2f*)(out + (size_t)a * EMB);
#pragma unroll
  for (int j = 0; j < 16; ++j)
    dst[j] = __builtin_elementwise_max(o2[j], z);
}

extern "C" void kernel_launch(void* const* d_in, const int* in_sizes, int n_in,
                              void* d_out, int out_size, void* d_ws, size_t ws_size,
                              hipStream_t stream) {
  const float* x_c = (const float*)d_in[0];
  const float* x_v = (const float*)d_in[1];
  const float* x_a = (const float*)d_in[2];
  const int* c2v_s = (const int*)d_in[3];
  const int* c2v_t = (const int*)d_in[4];
  const int* a2v_s = (const int*)d_in[5];
  const int* a2v_t = (const int*)d_in[6];
  const float* ea_c2v = (const float*)d_in[7];
  const float* ea_a2v = (const float*)d_in[8];
  const float* gv_W1 = (const float*)d_in[9];
  const float* gv_b1 = (const float*)d_in[10];
  const float* gv_W2 = (const float*)d_in[11];
  const float* gv_b2 = (const float*)d_in[12];
  const float* hv_W1 = (const float*)d_in[13];
  const float* hv_b1 = (const float*)d_in[14];
  const float* hv_W2 = (const float*)d_in[15];
  const float* hv_b2 = (const float*)d_in[16];
  const float* fv_W1 = (const float*)d_in[17];
  const float* fv_b1 = (const float*)d_in[18];
  const float* fv_W2 = (const float*)d_in[19];
  const float* fv_b2 = (const float*)d_in[20];
  const float* ga_W1 = (const float*)d_in[21];
  const float* ga_b1 = (const float*)d_in[22];
  const float* ga_W2 = (const float*)d_in[23];
  const float* ga_b2 = (const float*)d_in[24];
  const float* fa_W1 = (const float*)d_in[25];
  const float* fa_b1 = (const float*)d_in[26];
  const float* fa_W2 = (const float*)d_in[27];
  const float* fa_b2 = (const float*)d_in[28];

  // ---- workspace layout: ~38.3 MB (proven envelope ~39.9 MB) ----
  int* ip = (int*)d_ws;
  int* deg_g = ip;                  // 100000
  int* deg_h = deg_g + N_V;         // 100000
  int* deg_a = deg_h + N_V;         // 5000
  int* ctr = deg_a + N_A;           // 4
  float* hacc = (float*)(ctr + 4);              // N_V*32 (becomes fv in-place)
  float* hacc_a = hacc + (size_t)N_V * EMB;     // N_A*32
  int* off_g = (int*)(hacc_a + (size_t)N_A * EMB);  // 100000
  int* off_h = off_g + N_V;                         // 100000
  int* off_a = off_h + N_V;                         // 5000
  // Region B' (4.0M ints = 16 MB), time-multiplexed payload:
  //   phase g: t_g[1.6M] + ea_g[1.6M] + s_g[1.6M ushort]
  //   phase h: t_h[1.0M] + ea_h[1.0M] + s_h[1.0M ushort]
  //   phase a: t_a[1.0M] + ea_a[1.0M] + key_a[1.0M ushort]
  int* B = off_a + N_A;
  int* t_g = B;
  float* ea_g = (float*)(B + E_C2V);
  unsigned short* s_g = (unsigned short*)(B + 2 * E_C2V);
  int* t_h = B;
  float* ea_h = (float*)(B + E_A2V);
  unsigned short* s_h = (unsigned short*)(B + 2 * E_A2V);
  int* t_a = B;
  float* ea_a = (float*)(B + E_A2V);
  unsigned short* key_a = (unsigned short*)(B + 2 * E_A2V);
  // rank arrays (ushort; written by counts, consumed by the fills)
  unsigned short* rank_g = (unsigned short*)(B + 4 * (E_C2V / 2 * 5 / 4) == 0
                                                 ? B  // (never taken)
                                                 : B + 4000000);  // after B' (4.0M ints)
  rank_g = (unsigned short*)(B + 4000000);
  unsigned short* rank_h = rank_g + E_C2V;
  unsigned short* rank_a = rank_h + E_A2V;

  hipMemsetAsync(d_ws, 0,
                 (size_t)205004 * sizeof(int) +
                     (size_t)(N_V + N_A) * EMB * sizeof(float),
                 stream);

  // degrees + ranks (single pass, 1 thread/edge)
  k_counts<<<NCH, 256, 0, stream>>>(c2v_t, a2v_t, a2v_s, deg_g, deg_h, deg_a,
                                    rank_g, rank_h, rank_a);
  k_allocs<<<2 * NBV + NBA, 256, 0, stream>>>(deg_g, off_g, deg_h, off_h,
                                              deg_a, off_a, ctr);
  // g side: payload fill -> edge MLP + reduce -> hacc
  k_fill_g<<<8 * NCH, 256, 0, stream>>>(c2v_t, c2v_s, ea_c2v, off_g, rank_g,
                                        t_g, s_g, ea_g);
  k_edge_v<0><<<E_C2V / 256, 256, 0, stream>>>(
      E_C2V, t_g, s_g, ea_g, x_v, x_c,
      gv_W1, gv_b1, gv_W2, gv_b2, fv_W1 + (size_t)D_V * EMB, deg_g, hacc);
  // h side (reuses B')
  k_fill_h<<<8 * NCHA, 256, 0, stream>>>(a2v_t, a2v_s, ea_a2v, off_h, rank_h,
                                         t_h, s_h, ea_h);
  k_edge_v<1><<<(E_A2V + 255) / 256, 256, 0, stream>>>(
      E_A2V, t_h, s_h, ea_h, x_v, x_a,
      hv_W1, hv_b1, hv_W2, hv_b2, fv_W1 + (size_t)(D_V + EMB) * EMB, deg_h,
      hacc);
  // f_v in-place: hacc rows become fv rows
  k_node_fv<<<(N_V + 255) / 256, 256, 0, stream>>>(
      x_v, hacc, fv_W1, fv_b1, fv_W2, fv_b2);
  // a side (reuses B'): payload fill -> edge MLP + reduce -> hacc_a
  k_fill_a<<<8 * NCHA, 256, 0, stream>>>(a2v_s, a2v_t, ea_a2v, off_a, rank_a,
                                         key_a, t_a, ea_a);
  k_edge_a<<<(E_A2V + 255) / 256, 256, 0, stream>>>(
      key_a, t_a, ea_a, x_a, hacc,
      ga_W1, ga_b1, ga_W2, ga_b2, fa_W1 + (size_t)D_A * EMB, deg_a, hacc_a);
  // f_a -> out
  k_node_fa<<<(N_A + 255) / 256, 256, 0, stream>>>(
      x_a, hacc_a, fa_W1, fa_b1, fa_W2, fa_b2, (float*)d_out);
}

// Round 15
// 731.693 us; speedup vs baseline: 1.1748x; 1.0509x over previous
//
#include <hip/hip_runtime.h>

// Problem constants (from reference)
#define N_C 50000
#define N_V 100000
#define N_A 5000
#define E_C2V 1600000
#define E_A2V 1000000
#define D_V 13
#define D_C 14
#define D_A 14
#define EMB 32

// Residue-major node-index permutation (XCD-local CSR lines; round 8).
#define PV(t) (((t) >> 3) + ((t)&7) * (N_V / 8))  // N_V/8 = 12500
#define PA(t) (((t) >> 3) + ((t)&7) * (N_A / 8))  // N_A/8 = 625
#define NCH (E_C2V / 256)                         // 6250 chunks, exact
#define NCHA ((E_A2V + 255) / 256)                // 3907

typedef float v2f __attribute__((ext_vector_type(2)));
typedef unsigned long long u64;

// Pack (key_hi:17b, key_lo:16b, ea as bf16 RNE) into one u64.
__device__ __forceinline__ u64 pack_edge(int hi, int lo, float ea) {
  unsigned b = __float_as_uint(ea);
  b += 0x7FFFu + ((b >> 16) & 1u);  // round-to-nearest-even to bf16
  return ((u64)(unsigned)hi << 32) | ((u64)(unsigned)(lo & 0xFFFF) << 16) |
         (u64)(b >> 16);
}

// h2[j] (16 x float2 = 32 channels) += v * Wrow[2j..2j+1] via v_pk_fma_f32.
__device__ __forceinline__ void accrow2(v2f* __restrict__ h, float v,
                                        const float* __restrict__ Wrow) {
  const v2f* w = (const v2f*)Wrow;
  v2f vv = {v, v};
#pragma unroll
  for (int j = 0; j < 16; ++j) h[j] = __builtin_elementwise_fma(vv, w[j], h[j]);
}

__device__ __forceinline__ void relu2(v2f* __restrict__ h) {
  v2f z = {0.0f, 0.0f};
#pragma unroll
  for (int j = 0; j < 16; ++j) h[j] = __builtin_elementwise_max(h[j], z);
}

__device__ __forceinline__ void layer2(v2f* __restrict__ o2,
                                       const v2f* __restrict__ h,
                                       const float* __restrict__ W2,
                                       const float* __restrict__ b2) {
  const v2f* b = (const v2f*)b2;
#pragma unroll
  for (int j = 0; j < 16; ++j) o2[j] = b[j];
#pragma unroll
  for (int k = 0; k < EMB; ++k) {
    float hk = h[k >> 1][k & 1];
    accrow2(o2, hk, W2 + k * EMB);
  }
}

// -------- degree histograms + per-edge rank capture (atomicAdd return).
__global__ __launch_bounds__(256) void k_counts(
    const int* __restrict__ c2v_t, const int* __restrict__ a2v_t,
    const int* __restrict__ a2v_s, int* __restrict__ deg_g,
    int* __restrict__ deg_h, int* __restrict__ deg_a,
    unsigned short* __restrict__ rank_g, unsigned short* __restrict__ rank_h,
    unsigned short* __restrict__ rank_a) {
  int e = blockIdx.x * 256 + threadIdx.x;  // grid exact: E_C2V % 256 == 0
  int t = c2v_t[e];
  rank_g[e] = (unsigned short)atomicAdd(&deg_g[PV(t)], 1);
  if (e < E_A2V) {
    int th = a2v_t[e];
    rank_h[e] = (unsigned short)atomicAdd(&deg_h[PV(th)], 1);
    int ta = a2v_s[e];
    rank_a[e] = (unsigned short)atomicAdd(&deg_a[PA(ta)], 1);
  }
}

// -------- merged slot allocation (order-agnostic disjoint ranges)
#define NBV ((N_V + 255) / 256)  // 391
#define NBA ((N_A + 255) / 256)  // 20
__global__ __launch_bounds__(256) void k_allocs(
    const int* __restrict__ deg_g, int* __restrict__ off_g,
    const int* __restrict__ deg_h, int* __restrict__ off_h,
    const int* __restrict__ deg_a, int* __restrict__ off_a,
    int* __restrict__ ctr) {
  const int* deg;
  int* off;
  int* c;
  int i, n;
  if (blockIdx.x < NBV) {
    i = blockIdx.x * 256 + threadIdx.x;
    deg = deg_g; off = off_g; c = ctr + 0; n = N_V;
  } else if (blockIdx.x < 2 * NBV) {
    i = (blockIdx.x - NBV) * 256 + threadIdx.x;
    deg = deg_h; off = off_h; c = ctr + 1; n = N_V;
  } else {
    i = (blockIdx.x - 2 * NBV) * 256 + threadIdx.x;
    deg = deg_a; off = off_a; c = ctr + 2; n = N_A;
  }
  int lane = threadIdx.x & 63;
  int d = (i < n) ? deg[i] : 0;
  int v = d;
#pragma unroll
  for (int s = 1; s < 64; s <<= 1) {
    int t = __shfl_up(v, s, 64);
    if (lane >= s) v += t;
  }
  int total = __shfl(v, 63, 64);
  int base = 0;
  if (lane == 63) base = atomicAdd(c, total);
  base = __shfl(base, 63, 64);
  if (i < n) off[i] = base + v - d;
}

// -------- atomic-free payload fills: ONE packed 8-B scattered store/edge.
// pos = off[key] + rank[e]; residue-partitioned so scatter lines stay
// XCD-local (round 8). Replaces r14's 3 stores (incl. a 2-B ushort) with
// a single dwordx2 store; edge kernels get one coalesced 8-B load.
__global__ __launch_bounds__(256) void k_fill_g(
    const int* __restrict__ c2v_t, const int* __restrict__ c2v_s,
    const float* __restrict__ ea, const int* __restrict__ off_g,
    const unsigned short* __restrict__ rank_g, u64* __restrict__ pay) {
  int res = blockIdx.x & 7;
  int e = (blockIdx.x >> 3) * 256 + threadIdx.x;  // 8*NCH grid, exact
  int t = c2v_t[e];
  if ((t & 7) == res) {
    int pos = off_g[PV(t)] + rank_g[e];
    pay[pos] = pack_edge(t, c2v_s[e], ea[e]);  // s < 50000 < 2^16
  }
}

__global__ __launch_bounds__(256) void k_fill_h(
    const int* __restrict__ a2v_t, const int* __restrict__ a2v_s,
    const float* __restrict__ ea, const int* __restrict__ off_h,
    const unsigned short* __restrict__ rank_h, u64* __restrict__ pay) {
  int res = blockIdx.x & 7;
  int e = (blockIdx.x >> 3) * 256 + threadIdx.x;
  if (e >= E_A2V) return;
  int t = a2v_t[e];
  if ((t & 7) == res) {
    int pos = off_h[PV(t)] + rank_h[e];
    pay[pos] = pack_edge(t, a2v_s[e], ea[e]);  // s < 5000
  }
}

__global__ __launch_bounds__(256) void k_fill_a(
    const int* __restrict__ a2v_s, const int* __restrict__ a2v_t,
    const float* __restrict__ ea, const int* __restrict__ off_a,
    const unsigned short* __restrict__ rank_a, u64* __restrict__ pay) {
  int res = blockIdx.x & 7;
  int e = (blockIdx.x >> 3) * 256 + threadIdx.x;
  if (e >= E_A2V) return;
  int a = a2v_s[e];
  if ((a & 7) == res) {
    int pos = off_a[PA(a)] + rank_a[e];
    pay[pos] = pack_edge(a2v_t[e], a, ea[e]);  // hi=t (17b), lo=a (<5000)
  }
}

// -------- edge-parallel v-side edge MLP (FIN=28, packed) + per-wave LDS
// segmented reduce + projection through the f_v W1 slice -> hacc.
// Per-edge input: one coalesced 8-B packed payload (key=hi, s=lo, ea=bf16).
template <int ADDMODE>
__global__ __launch_bounds__(256) void k_edge_v(
    int E, const u64* __restrict__ pay,
    const float* __restrict__ x_t,   // variable-node feats (13)
    const float* __restrict__ x_s,   // source feats (14), rows 8B-aligned
    const float* __restrict__ W1, const float* __restrict__ b1,
    const float* __restrict__ W2, const float* __restrict__ b2,
    const float* __restrict__ Wp,    // fW1 + (13 or 45)*32 projection slice
    const int* __restrict__ deg,     // residue-major indexed
    float* __restrict__ hacc) {
  __shared__ float vals[4][64][34];
  __shared__ int nidl[4][64];
  __shared__ float segx[4][32];
  int wv = threadIdx.x >> 6;
  int lane = threadIdx.x & 63;
  int slot = blockIdx.x * 256 + threadIdx.x;
  if ((slot & ~63) >= E) return;  // wave-uniform exit (E % 64 == 0)

  u64 p = pay[slot];
  int t = (int)(p >> 32);
  int s = (int)((p >> 16) & 0xFFFFull);
  float eav = __uint_as_float((unsigned)(p & 0xFFFFull) << 16);
  const float* xt = x_t + (size_t)t * D_V;

  v2f h[16];
  const v2f* b1v = (const v2f*)b1;
#pragma unroll
  for (int j = 0; j < 16; ++j) h[j] = b1v[j];
#pragma unroll
  for (int i = 0; i < D_V; ++i) accrow2(h, xt[i], W1 + i * EMB);
  const float2* xs2 = (const float2*)(x_s + (size_t)s * D_C);
#pragma unroll
  for (int i = 0; i < 7; ++i) {
    float2 wv2 = xs2[i];
    accrow2(h, wv2.x, W1 + (D_V + 2 * i) * EMB);
    accrow2(h, wv2.y, W1 + (D_V + 2 * i + 1) * EMB);
  }
  accrow2(h, eav, W1 + 27 * EMB);
  relu2(h);
  v2f o2[16];
  layer2(o2, h, W2, b2);
  {
    v2f z = {0.0f, 0.0f};
    v2f* vr = (v2f*)&vals[wv][lane][0];
#pragma unroll
    for (int j = 0; j < 16; ++j) vr[j] = __builtin_elementwise_max(o2[j], z);
  }
  nidl[wv][lane] = t;
  // wave-synchronous segmented reduce (32 channel-lanes)
  if (lane < EMB) {
    int j = lane;
    float acc = 0.0f;
    int r0 = 0;
    for (int r = 0; r < 64; ++r) {
      acc += vals[wv][r][j];
      int cur = nidl[wv][r];
      bool flush = (r == 63) || (nidl[wv][r + 1] != cur);
      if (flush) {  // wave-uniform
        float inv = 1.0f / fmaxf((float)deg[PV(cur)], 1.0f);
        segx[wv][j] = acc * inv;
        float out = 0.0f;
#pragma unroll
        for (int k = 0; k < EMB; ++k)
          out = fmaf(segx[wv][k], Wp[k * EMB + j], out);
        float* dst = &hacc[(size_t)cur * EMB + j];
        if (r0 > 0 && r < 63) {  // interior: sole writer for this row
          if (ADDMODE) out += *dst;
          *dst = out;
        } else {
          atomicAdd(dst, out);
        }
        acc = 0.0f;
        r0 = r + 1;
      }
    }
  }
}

// -------- edge-parallel a-side g_a MLP (FIN=47, packed) + reduce -> hacc_a
__global__ __launch_bounds__(256) void k_edge_a(
    const u64* __restrict__ pay,
    const float* __restrict__ xa_g, const float* __restrict__ fv,
    const float* __restrict__ W1, const float* __restrict__ b1,
    const float* __restrict__ W2, const float* __restrict__ b2,
    const float* __restrict__ Wp,   // fa_W1 + 14*32
    const int* __restrict__ deg,
    float* __restrict__ hacc_a) {
  __shared__ float vals[4][64][34];
  __shared__ int nidl[4][64];
  __shared__ float segx[4][32];
  int wv = threadIdx.x >> 6;
  int lane = threadIdx.x & 63;
  int slot = blockIdx.x * 256 + threadIdx.x;
  if ((slot & ~63) >= E_A2V) return;

  u64 p = pay[slot];
  int t = (int)(p >> 32);
  int a = (int)((p >> 16) & 0xFFFFull);
  float eav = __uint_as_float((unsigned)(p & 0xFFFFull) << 16);

  v2f h[16];
  const v2f* b1v = (const v2f*)b1;
#pragma unroll
  for (int j = 0; j < 16; ++j) h[j] = b1v[j];
  const float2* ps2 = (const float2*)(xa_g + (size_t)a * D_A);
#pragma unroll
  for (int i = 0; i < 7; ++i) {
    float2 wv2 = ps2[i];
    accrow2(h, wv2.x, W1 + (2 * i) * EMB);
    accrow2(h, wv2.y, W1 + (2 * i + 1) * EMB);
  }
  const float4* pf = (const float4*)(fv + (size_t)t * EMB);
#pragma unroll
  for (int q = 0; q < 8; ++q) {
    float4 f = pf[q];
    accrow2(h, f.x, W1 + (D_A + 4 * q) * EMB);
    accrow2(h, f.y, W1 + (D_A + 4 * q + 1) * EMB);
    accrow2(h, f.z, W1 + (D_A + 4 * q + 2) * EMB);
    accrow2(h, f.w, W1 + (D_A + 4 * q + 3) * EMB);
  }
  accrow2(h, eav, W1 + 46 * EMB);
  relu2(h);
  v2f o2[16];
  layer2(o2, h, W2, b2);
  {
    v2f z = {0.0f, 0.0f};
    v2f* vr = (v2f*)&vals[wv][lane][0];
#pragma unroll
    for (int j = 0; j < 16; ++j) vr[j] = __builtin_elementwise_max(o2[j], z);
  }
  nidl[wv][lane] = a;
  if (lane < EMB) {
    int j = lane;
    float acc = 0.0f;
    int r0 = 0;
    for (int r = 0; r < 64; ++r) {
      acc += vals[wv][r][j];
      int cur = nidl[wv][r];
      bool flush = (r == 63) || (nidl[wv][r + 1] != cur);
      if (flush) {
        float inv = 1.0f / fmaxf((float)deg[PA(cur)], 1.0f);
        segx[wv][j] = acc * inv;
        float out = 0.0f;
#pragma unroll
        for (int k = 0; k < EMB; ++k)
          out = fmaf(segx[wv][k], Wp[k * EMB + j], out);
        float* dst = &hacc_a[(size_t)cur * EMB + j];
        if (r0 > 0 && r < 63) {
          *dst = out;  // sole writer (zeroed buffer, single dispatch)
        } else {
          atomicAdd(dst, out);
        }
        acc = 0.0f;
        r0 = r + 1;
      }
    }
  }
}

// -------- f_v node MLP, IN-PLACE on hacc (same thread reads+writes row v).
__global__ __launch_bounds__(256) void k_node_fv(
    const float* __restrict__ xv_g, float* hf,
    const float* __restrict__ fW1, const float* __restrict__ fb1,
    const float* __restrict__ fW2, const float* __restrict__ fb2) {
  int v = blockIdx.x * blockDim.x + threadIdx.x;
  if (v >= N_V) return;
  v2f* row = (v2f*)(hf + (size_t)v * EMB);
  const v2f* bv = (const v2f*)fb1;
  v2f h[16];
#pragma unroll
  for (int j = 0; j < 16; ++j) h[j] = bv[j] + row[j];
  const float* pv = xv_g + (size_t)v * D_V;
#pragma unroll
  for (int i = 0; i < D_V; ++i) accrow2(h, pv[i], fW1 + i * EMB);
  relu2(h);
  v2f o2[16];
  layer2(o2, h, fW2, fb2);
  v2f z = {0.0f, 0.0f};
#pragma unroll
  for (int j = 0; j < 16; ++j)
    row[j] = __builtin_elementwise_max(o2[j], z);  // relu_out (+idempotent)
}

// -------- f_a node MLP on pre-accumulated hidden -> d_out (packed)
__global__ __launch_bounds__(256) void k_node_fa(
    const float* __restrict__ xa, const float* __restrict__ hacc_a,
    const float* __restrict__ W1, const float* __restrict__ b1,
    const float* __restrict__ W2, const float* __restrict__ b2,
    float* __restrict__ out) {
  int a = blockIdx.x * blockDim.x + threadIdx.x;
  if (a >= N_A) return;
  const v2f* hr = (const v2f*)(hacc_a + (size_t)a * EMB);
  const v2f* bv = (const v2f*)b1;
  v2f h[16];
#pragma unroll
  for (int j = 0; j < 16; ++j) h[j] = bv[j] + hr[j];
  const float2* pa = (const float2*)(xa + (size_t)a * D_A);
#pragma unroll
  for (int i = 0; i < 7; ++i) {
    float2 w = pa[i];
    accrow2(h, w.x, W1 + (2 * i) * EMB);
    accrow2(h, w.y, W1 + (2 * i + 1) * EMB);
  }
  relu2(h);
  v2f o2[16];
  layer2(o2, h, W2, b2);
  v2f z = {0.0f, 0.0f};
  v2f* dst = (v2f*)(out + (size_t)a * EMB);
#pragma unroll
  for (int j = 0; j < 16; ++j)
    dst[j] = __builtin_elementwise_max(o2[j], z);
}

extern "C" void kernel_launch(void* const* d_in, const int* in_sizes, int n_in,
                              void* d_out, int out_size, void* d_ws, size_t ws_size,
                              hipStream_t stream) {
  const float* x_c = (const float*)d_in[0];
  const float* x_v = (const float*)d_in[1];
  const float* x_a = (const float*)d_in[2];
  const int* c2v_s = (const int*)d_in[3];
  const int* c2v_t = (const int*)d_in[4];
  const int* a2v_s = (const int*)d_in[5];
  const int* a2v_t = (const int*)d_in[6];
  const float* ea_c2v = (const float*)d_in[7];
  const float* ea_a2v = (const float*)d_in[8];
  const float* gv_W1 = (const float*)d_in[9];
  const float* gv_b1 = (const float*)d_in[10];
  const float* gv_W2 = (const float*)d_in[11];
  const float* gv_b2 = (const float*)d_in[12];
  const float* hv_W1 = (const float*)d_in[13];
  const float* hv_b1 = (const float*)d_in[14];
  const float* hv_W2 = (const float*)d_in[15];
  const float* hv_b2 = (const float*)d_in[16];
  const float* fv_W1 = (const float*)d_in[17];
  const float* fv_b1 = (const float*)d_in[18];
  const float* fv_W2 = (const float*)d_in[19];
  const float* fv_b2 = (const float*)d_in[20];
  const float* ga_W1 = (const float*)d_in[21];
  const float* ga_b1 = (const float*)d_in[22];
  const float* ga_W2 = (const float*)d_in[23];
  const float* ga_b2 = (const float*)d_in[24];
  const float* fa_W1 = (const float*)d_in[25];
  const float* fa_b1 = (const float*)d_in[26];
  const float* fa_W2 = (const float*)d_in[27];
  const float* fa_b2 = (const float*)d_in[28];

  // ---- workspace layout: ~35.1 MB (proven envelope ~39.9 MB) ----
  int* ip = (int*)d_ws;
  int* deg_g = ip;                  // 100000
  int* deg_h = deg_g + N_V;         // 100000
  int* deg_a = deg_h + N_V;         // 5000
  int* ctr = deg_a + N_A;           // 4
  float* hacc = (float*)(ctr + 4);              // N_V*32 (becomes fv in-place)
  float* hacc_a = hacc + (size_t)N_V * EMB;     // N_A*32
  int* off_g = (int*)(hacc_a + (size_t)N_A * EMB);  // 100000
  int* off_h = off_g + N_V;                         // 100000
  int* off_a = off_h + N_V;                         // 5000
  // Packed payload region (1.6M u64 = 12.8 MB), time-multiplexed g -> h -> a.
  // Byte offset of payB: 3,770,004 ints * 4 = 15,080,016 B (divisible by 8).
  u64* payB = (u64*)(off_a + N_A);
  // rank arrays (ushort; written by counts, consumed by fills)
  unsigned short* rank_g = (unsigned short*)(payB + E_C2V);  // 1.6M
  unsigned short* rank_h = rank_g + E_C2V;                   // 1.0M
  unsigned short* rank_a = rank_h + E_A2V;                   // 1.0M

  hipMemsetAsync(d_ws, 0,
                 (size_t)205004 * sizeof(int) +
                     (size_t)(N_V + N_A) * EMB * sizeof(float),
                 stream);

  // degrees + ranks (single pass, 1 thread/edge)
  k_counts<<<NCH, 256, 0, stream>>>(c2v_t, a2v_t, a2v_s, deg_g, deg_h, deg_a,
                                    rank_g, rank_h, rank_a);
  k_allocs<<<2 * NBV + NBA, 256, 0, stream>>>(deg_g, off_g, deg_h, off_h,
                                              deg_a, off_a, ctr);
  // g side: packed payload fill -> edge MLP + reduce -> hacc
  k_fill_g<<<8 * NCH, 256, 0, stream>>>(c2v_t, c2v_s, ea_c2v, off_g, rank_g,
                                        payB);
  k_edge_v<0><<<E_C2V / 256, 256, 0, stream>>>(
      E_C2V, payB, x_v, x_c,
      gv_W1, gv_b1, gv_W2, gv_b2, fv_W1 + (size_t)D_V * EMB, deg_g, hacc);
  // h side (reuses payload region)
  k_fill_h<<<8 * NCHA, 256, 0, stream>>>(a2v_t, a2v_s, ea_a2v, off_h, rank_h,
                                         payB);
  k_edge_v<1><<<NCHA, 256, 0, stream>>>(
      E_A2V, payB, x_v, x_a,
      hv_W1, hv_b1, hv_W2, hv_b2, fv_W1 + (size_t)(D_V + EMB) * EMB, deg_h,
      hacc);
  // f_v in-place: hacc rows become fv rows
  k_node_fv<<<(N_V + 255) / 256, 256, 0, stream>>>(
      x_v, hacc, fv_W1, fv_b1, fv_W2, fv_b2);
  // a side (reuses payload region)
  k_fill_a<<<8 * NCHA, 256, 0, stream>>>(a2v_s, a2v_t, ea_a2v, off_a, rank_a,
                                         payB);
  k_edge_a<<<NCHA, 256, 0, stream>>>(
      payB, x_a, hacc,
      ga_W1, ga_b1, ga_W2, ga_b2, fa_W1 + (size_t)D_A * EMB, deg_a, hacc_a);
  // f_a -> out
  k_node_fa<<<(N_A + 255) / 256, 256, 0, stream>>>(
      x_a, hacc_a, fa_W1, fa_b1, fa_W2, fa_b2, (float*)d_out);
}

// Round 16
// 705.622 us; speedup vs baseline: 1.2182x; 1.0369x over previous
//
#include <hip/hip_runtime.h>

// Problem constants (from reference)
#define N_C 50000
#define N_V 100000
#define N_A 5000
#define E_C2V 1600000
#define E_A2V 1000000
#define D_V 13
#define D_C 14
#define D_A 14
#define EMB 32

// Residue-major node-index permutation (XCD-local CSR lines; round 8).
#define PV(t) (((t) >> 3) + ((t)&7) * (N_V / 8))  // N_V/8 = 12500
#define PA(t) (((t) >> 3) + ((t)&7) * (N_A / 8))  // N_A/8 = 625
#define NCH (E_C2V / 256)                         // 6250 chunks, exact
#define NCHA ((E_A2V + 255) / 256)                // 3907

typedef float v2f __attribute__((ext_vector_type(2)));
typedef unsigned long long u64;

// Pack (key_hi:17b, key_lo:16b, ea as bf16 RNE) into one u64.
__device__ __forceinline__ u64 pack_edge(int hi, int lo, float ea) {
  unsigned b = __float_as_uint(ea);
  b += 0x7FFFu + ((b >> 16) & 1u);  // round-to-nearest-even to bf16
  return ((u64)(unsigned)hi << 32) | ((u64)(unsigned)(lo & 0xFFFF) << 16) |
         (u64)(b >> 16);
}

// Pack two floats to bf16 pair (RNE) in one uint: low=a, high=b.
__device__ __forceinline__ unsigned bf16pk(float a, float b) {
  unsigned ua = __float_as_uint(a);
  ua += 0x7FFFu + ((ua >> 16) & 1u);
  unsigned ub = __float_as_uint(b);
  ub += 0x7FFFu + ((ub >> 16) & 1u);
  return (ua >> 16) | (ub & 0xFFFF0000u);
}

// h2[j] (16 x float2 = 32 channels) += v * Wrow[2j..2j+1] via v_pk_fma_f32.
__device__ __forceinline__ void accrow2(v2f* __restrict__ h, float v,
                                        const float* __restrict__ Wrow) {
  const v2f* w = (const v2f*)Wrow;
  v2f vv = {v, v};
#pragma unroll
  for (int j = 0; j < 16; ++j) h[j] = __builtin_elementwise_fma(vv, w[j], h[j]);
}

__device__ __forceinline__ void relu2(v2f* __restrict__ h) {
  v2f z = {0.0f, 0.0f};
#pragma unroll
  for (int j = 0; j < 16; ++j) h[j] = __builtin_elementwise_max(h[j], z);
}

__device__ __forceinline__ void layer2(v2f* __restrict__ o2,
                                       const v2f* __restrict__ h,
                                       const float* __restrict__ W2,
                                       const float* __restrict__ b2) {
  const v2f* b = (const v2f*)b2;
#pragma unroll
  for (int j = 0; j < 16; ++j) o2[j] = b[j];
#pragma unroll
  for (int k = 0; k < EMB; ++k) {
    float hk = h[k >> 1][k & 1];
    accrow2(o2, hk, W2 + k * EMB);
  }
}

// -------- degree histograms + per-edge rank capture (atomicAdd return).
__global__ __launch_bounds__(256) void k_counts(
    const int* __restrict__ c2v_t, const int* __restrict__ a2v_t,
    const int* __restrict__ a2v_s, int* __restrict__ deg_g,
    int* __restrict__ deg_h, int* __restrict__ deg_a,
    unsigned short* __restrict__ rank_g, unsigned short* __restrict__ rank_h,
    unsigned short* __restrict__ rank_a) {
  int e = blockIdx.x * 256 + threadIdx.x;  // grid exact: E_C2V % 256 == 0
  int t = c2v_t[e];
  rank_g[e] = (unsigned short)atomicAdd(&deg_g[PV(t)], 1);
  if (e < E_A2V) {
    int th = a2v_t[e];
    rank_h[e] = (unsigned short)atomicAdd(&deg_h[PV(th)], 1);
    int ta = a2v_s[e];
    rank_a[e] = (unsigned short)atomicAdd(&deg_a[PA(ta)], 1);
  }
}

// -------- merged slot allocation (order-agnostic disjoint ranges)
#define NBV ((N_V + 255) / 256)  // 391
#define NBA ((N_A + 255) / 256)  // 20
__global__ __launch_bounds__(256) void k_allocs(
    const int* __restrict__ deg_g, int* __restrict__ off_g,
    const int* __restrict__ deg_h, int* __restrict__ off_h,
    const int* __restrict__ deg_a, int* __restrict__ off_a,
    int* __restrict__ ctr) {
  const int* deg;
  int* off;
  int* c;
  int i, n;
  if (blockIdx.x < NBV) {
    i = blockIdx.x * 256 + threadIdx.x;
    deg = deg_g; off = off_g; c = ctr + 0; n = N_V;
  } else if (blockIdx.x < 2 * NBV) {
    i = (blockIdx.x - NBV) * 256 + threadIdx.x;
    deg = deg_h; off = off_h; c = ctr + 1; n = N_V;
  } else {
    i = (blockIdx.x - 2 * NBV) * 256 + threadIdx.x;
    deg = deg_a; off = off_a; c = ctr + 2; n = N_A;
  }
  int lane = threadIdx.x & 63;
  int d = (i < n) ? deg[i] : 0;
  int v = d;
#pragma unroll
  for (int s = 1; s < 64; s <<= 1) {
    int t = __shfl_up(v, s, 64);
    if (lane >= s) v += t;
  }
  int total = __shfl(v, 63, 64);
  int base = 0;
  if (lane == 63) base = atomicAdd(c, total);
  base = __shfl(base, 63, 64);
  if (i < n) off[i] = base + v - d;
}

// -------- atomic-free payload fills: ONE packed 8-B scattered store/edge.
// pos = off[key] + rank[e]; residue-partitioned so scatter lines stay
// XCD-local (round 8).
__global__ __launch_bounds__(256) void k_fill_g(
    const int* __restrict__ c2v_t, const int* __restrict__ c2v_s,
    const float* __restrict__ ea, const int* __restrict__ off_g,
    const unsigned short* __restrict__ rank_g, u64* __restrict__ pay) {
  int res = blockIdx.x & 7;
  int e = (blockIdx.x >> 3) * 256 + threadIdx.x;  // 8*NCH grid, exact
  int t = c2v_t[e];
  if ((t & 7) == res) {
    int pos = off_g[PV(t)] + rank_g[e];
    pay[pos] = pack_edge(t, c2v_s[e], ea[e]);  // s < 50000 < 2^16
  }
}

// h and a fills merged: one pass over the a2v edge list fills both payloads.
__global__ __launch_bounds__(256) void k_fill_ha(
    const int* __restrict__ a2v_t, const int* __restrict__ a2v_s,
    const float* __restrict__ ea,
    const int* __restrict__ off_h, const unsigned short* __restrict__ rank_h,
    u64* __restrict__ pay_h,
    const int* __restrict__ off_a, const unsigned short* __restrict__ rank_a,
    u64* __restrict__ pay_a) {
  int res = blockIdx.x & 7;
  int e = (blockIdx.x >> 3) * 256 + threadIdx.x;
  if (e >= E_A2V) return;
  int t = a2v_t[e];
  int a = a2v_s[e];
  if ((t & 7) == res) {
    int pos = off_h[PV(t)] + rank_h[e];
    pay_h[pos] = pack_edge(t, a, ea[e]);  // s < 5000
  }
  if ((a & 7) == res) {
    int pos = off_a[PA(a)] + rank_a[e];
    pay_a[pos] = pack_edge(t, a, ea[e]);  // hi=t (17b), lo=a (<5000)
  }
}

// -------- edge-parallel v-side edge MLP (FIN=28, packed) + per-wave LDS
// segmented reduce + projection through the f_v W1 slice -> hacc.
// vals staged as bf16 pairs: LDS 36 KB -> ~19 KB, occupancy 4 -> ~8 blk/CU.
template <int ADDMODE>
__global__ __launch_bounds__(256) void k_edge_v(
    int E, const u64* __restrict__ pay,
    const float* __restrict__ x_t,   // variable-node feats (13)
    const float* __restrict__ x_s,   // source feats (14), rows 8B-aligned
    const float* __restrict__ W1, const float* __restrict__ b1,
    const float* __restrict__ W2, const float* __restrict__ b2,
    const float* __restrict__ Wp,    // fW1 + (13 or 45)*32 projection slice
    const int* __restrict__ deg,     // residue-major indexed
    float* __restrict__ hacc) {
  __shared__ unsigned short vals[4][64][34];  // bf16; stride 34 -> 4B-aligned rows
  __shared__ int nidl[4][64];
  __shared__ float segx[4][32];
  int wv = threadIdx.x >> 6;
  int lane = threadIdx.x & 63;
  int slot = blockIdx.x * 256 + threadIdx.x;
  if ((slot & ~63) >= E) return;  // wave-uniform exit (E % 64 == 0)

  u64 p = pay[slot];
  int t = (int)(p >> 32);
  int s = (int)((p >> 16) & 0xFFFFull);
  float eav = __uint_as_float((unsigned)(p & 0xFFFFull) << 16);
  const float* xt = x_t + (size_t)t * D_V;

  v2f h[16];
  const v2f* b1v = (const v2f*)b1;
#pragma unroll
  for (int j = 0; j < 16; ++j) h[j] = b1v[j];
#pragma unroll
  for (int i = 0; i < D_V; ++i) accrow2(h, xt[i], W1 + i * EMB);
  const float2* xs2 = (const float2*)(x_s + (size_t)s * D_C);
#pragma unroll
  for (int i = 0; i < 7; ++i) {
    float2 wv2 = xs2[i];
    accrow2(h, wv2.x, W1 + (D_V + 2 * i) * EMB);
    accrow2(h, wv2.y, W1 + (D_V + 2 * i + 1) * EMB);
  }
  accrow2(h, eav, W1 + 27 * EMB);
  relu2(h);
  v2f o2[16];
  layer2(o2, h, W2, b2);
  relu2(o2);
  {
    unsigned* vr = (unsigned*)&vals[wv][lane][0];  // 68*lane bytes: 4B-aligned
#pragma unroll
    for (int j = 0; j < 16; ++j) vr[j] = bf16pk(o2[j].x, o2[j].y);
  }
  nidl[wv][lane] = t;
  // wave-synchronous segmented reduce (32 channel-lanes)
  if (lane < EMB) {
    int j = lane;
    float acc = 0.0f;
    int r0 = 0;
    for (int r = 0; r < 64; ++r) {
      acc += __uint_as_float((unsigned)vals[wv][r][j] << 16);
      int cur = nidl[wv][r];
      bool flush = (r == 63) || (nidl[wv][r + 1] != cur);
      if (flush) {  // wave-uniform
        float inv = 1.0f / fmaxf((float)deg[PV(cur)], 1.0f);
        segx[wv][j] = acc * inv;
        float out = 0.0f;
#pragma unroll
        for (int k = 0; k < EMB; ++k)
          out = fmaf(segx[wv][k], Wp[k * EMB + j], out);
        float* dst = &hacc[(size_t)cur * EMB + j];
        if (r0 > 0 && r < 63) {  // interior: sole writer for this row
          if (ADDMODE) out += *dst;
          *dst = out;
        } else {
          atomicAdd(dst, out);
        }
        acc = 0.0f;
        r0 = r + 1;
      }
    }
  }
}

// -------- edge-parallel a-side g_a MLP (FIN=47, packed) + reduce -> hacc_a
__global__ __launch_bounds__(256) void k_edge_a(
    const u64* __restrict__ pay,
    const float* __restrict__ xa_g, const float* __restrict__ fv,
    const float* __restrict__ W1, const float* __restrict__ b1,
    const float* __restrict__ W2, const float* __restrict__ b2,
    const float* __restrict__ Wp,   // fa_W1 + 14*32
    const int* __restrict__ deg,
    float* __restrict__ hacc_a) {
  __shared__ unsigned short vals[4][64][34];
  __shared__ int nidl[4][64];
  __shared__ float segx[4][32];
  int wv = threadIdx.x >> 6;
  int lane = threadIdx.x & 63;
  int slot = blockIdx.x * 256 + threadIdx.x;
  if ((slot & ~63) >= E_A2V) return;

  u64 p = pay[slot];
  int t = (int)(p >> 32);
  int a = (int)((p >> 16) & 0xFFFFull);
  float eav = __uint_as_float((unsigned)(p & 0xFFFFull) << 16);

  v2f h[16];
  const v2f* b1v = (const v2f*)b1;
#pragma unroll
  for (int j = 0; j < 16; ++j) h[j] = b1v[j];
  const float2* ps2 = (const float2*)(xa_g + (size_t)a * D_A);
#pragma unroll
  for (int i = 0; i < 7; ++i) {
    float2 wv2 = ps2[i];
    accrow2(h, wv2.x, W1 + (2 * i) * EMB);
    accrow2(h, wv2.y, W1 + (2 * i + 1) * EMB);
  }
  const float4* pf = (const float4*)(fv + (size_t)t * EMB);
#pragma unroll
  for (int q = 0; q < 8; ++q) {
    float4 f = pf[q];
    accrow2(h, f.x, W1 + (D_A + 4 * q) * EMB);
    accrow2(h, f.y, W1 + (D_A + 4 * q + 1) * EMB);
    accrow2(h, f.z, W1 + (D_A + 4 * q + 2) * EMB);
    accrow2(h, f.w, W1 + (D_A + 4 * q + 3) * EMB);
  }
  accrow2(h, eav, W1 + 46 * EMB);
  relu2(h);
  v2f o2[16];
  layer2(o2, h, W2, b2);
  relu2(o2);
  {
    unsigned* vr = (unsigned*)&vals[wv][lane][0];
#pragma unroll
    for (int j = 0; j < 16; ++j) vr[j] = bf16pk(o2[j].x, o2[j].y);
  }
  nidl[wv][lane] = a;
  if (lane < EMB) {
    int j = lane;
    float acc = 0.0f;
    int r0 = 0;
    for (int r = 0; r < 64; ++r) {
      acc += __uint_as_float((unsigned)vals[wv][r][j] << 16);
      int cur = nidl[wv][r];
      bool flush = (r == 63) || (nidl[wv][r + 1] != cur);
      if (flush) {
        float inv = 1.0f / fmaxf((float)deg[PA(cur)], 1.0f);
        segx[wv][j] = acc * inv;
        float out = 0.0f;
#pragma unroll
        for (int k = 0; k < EMB; ++k)
          out = fmaf(segx[wv][k], Wp[k * EMB + j], out);
        float* dst = &hacc_a[(size_t)cur * EMB + j];
        if (r0 > 0 && r < 63) {
          *dst = out;  // sole writer (zeroed buffer, single dispatch)
        } else {
          atomicAdd(dst, out);
        }
        acc = 0.0f;
        r0 = r + 1;
      }
    }
  }
}

// -------- f_v node MLP, IN-PLACE on hacc (same thread reads+writes row v).
__global__ __launch_bounds__(256) void k_node_fv(
    const float* __restrict__ xv_g, float* hf,
    const float* __restrict__ fW1, const float* __restrict__ fb1,
    const float* __restrict__ fW2, const float* __restrict__ fb2) {
  int v = blockIdx.x * blockDim.x + threadIdx.x;
  if (v >= N_V) return;
  v2f* row = (v2f*)(hf + (size_t)v * EMB);
  const v2f* bv = (const v2f*)fb1;
  v2f h[16];
#pragma unroll
  for (int j = 0; j < 16; ++j) h[j] = bv[j] + row[j];
  const float* pv = xv_g + (size_t)v * D_V;
#pragma unroll
  for (int i = 0; i < D_V; ++i) accrow2(h, pv[i], fW1 + i * EMB);
  relu2(h);
  v2f o2[16];
  layer2(o2, h, fW2, fb2);
  v2f z = {0.0f, 0.0f};
#pragma unroll
  for (int j = 0; j < 16; ++j)
    row[j] = __builtin_elementwise_max(o2[j], z);  // relu_out (+idempotent)
}

// -------- f_a node MLP on pre-accumulated hidden -> d_out (packed)
__global__ __launch_bounds__(256) void k_node_fa(
    const float* __restrict__ xa, const float* __restrict__ hacc_a,
    const float* __restrict__ W1, const float* __restrict__ b1,
    const float* __restrict__ W2, const float* __restrict__ b2,
    float* __restrict__ out) {
  int a = blockIdx.x * blockDim.x + threadIdx.x;
  if (a >= N_A) return;
  const v2f* hr = (const v2f*)(hacc_a + (size_t)a * EMB);
  const v2f* bv = (const v2f*)b1;
  v2f h[16];
#pragma unroll
  for (int j = 0; j < 16; ++j) h[j] = bv[j] + hr[j];
  const float2* pa = (const float2*)(xa + (size_t)a * D_A);
#pragma unroll
  for (int i = 0; i < 7; ++i) {
    float2 w = pa[i];
    accrow2(h, w.x, W1 + (2 * i) * EMB);
    accrow2(h, w.y, W1 + (2 * i + 1) * EMB);
  }
  relu2(h);
  v2f o2[16];
  layer2(o2, h, W2, b2);
  v2f z = {0.0f, 0.0f};
  v2f* dst = (v2f*)(out + (size_t)a * EMB);
#pragma unroll
  for (int j = 0; j < 16; ++j)
    dst[j] = __builtin_elementwise_max(o2[j], z);
}

extern "C" void kernel_launch(void* const* d_in, const int* in_sizes, int n_in,
                              void* d_out, int out_size, void* d_ws, size_t ws_size,
                              hipStream_t stream) {
  const float* x_c = (const float*)d_in[0];
  const float* x_v = (const float*)d_in[1];
  const float* x_a = (const float*)d_in[2];
  const int* c2v_s = (const int*)d_in[3];
  const int* c2v_t = (const int*)d_in[4];
  const int* a2v_s = (const int*)d_in[5];
  const int* a2v_t = (const int*)d_in[6];
  const float* ea_c2v = (const float*)d_in[7];
  const float* ea_a2v = (const float*)d_in[8];
  const float* gv_W1 = (const float*)d_in[9];
  const float* gv_b1 = (const float*)d_in[10];
  const float* gv_W2 = (const float*)d_in[11];
  const float* gv_b2 = (const float*)d_in[12];
  const float* hv_W1 = (const float*)d_in[13];
  const float* hv_b1 = (const float*)d_in[14];
  const float* hv_W2 = (const float*)d_in[15];
  const float* hv_b2 = (const float*)d_in[16];
  const float* fv_W1 = (const float*)d_in[17];
  const float* fv_b1 = (const float*)d_in[18];
  const float* fv_W2 = (const float*)d_in[19];
  const float* fv_b2 = (const float*)d_in[20];
  const float* ga_W1 = (const float*)d_in[21];
  const float* ga_b1 = (const float*)d_in[22];
  const float* ga_W2 = (const float*)d_in[23];
  const float* ga_b2 = (const float*)d_in[24];
  const float* fa_W1 = (const float*)d_in[25];
  const float* fa_b1 = (const float*)d_in[26];
  const float* fa_W2 = (const float*)d_in[27];
  const float* fa_b2 = (const float*)d_in[28];

  // ---- workspace layout: ~35.1 MB (proven envelope ~39.9 MB) ----
  int* ip = (int*)d_ws;
  int* deg_g = ip;                  // 100000
  int* deg_h = deg_g + N_V;         // 100000
  int* deg_a = deg_h + N_V;         // 5000
  int* ctr = deg_a + N_A;           // 4
  float* hacc = (float*)(ctr + 4);              // N_V*32 (becomes fv in-place)
  float* hacc_a = hacc + (size_t)N_V * EMB;     // N_A*32
  int* off_g = (int*)(hacc_a + (size_t)N_A * EMB);  // 100000
  int* off_h = off_g + N_V;                         // 100000
  int* off_a = off_h + N_V;                         // 5000
  // Packed payload region payB (1.6M u64 = 12.8 MB):
  //   phase g: pay_g = payB[0..1.6M)
  //   phase h/a (after edge_g): pay_h = payB[0..1.0M),
  //     pay_a = payB[1.0M..2.0M) -- upper 0.4M u64 overlays dead rank_g.
  u64* payB = (u64*)(off_a + N_A);  // byte offset 15,080,016 (8B-aligned)
  u64* pay_a = payB + E_A2V;
  // rank arrays (ushort; written by counts, consumed by fills)
  unsigned short* rank_g = (unsigned short*)(payB + E_C2V);  // 1.6M (dies after fill_g)
  unsigned short* rank_h = rank_g + E_C2V;                   // 1.0M
  unsigned short* rank_a = rank_h + E_A2V;                   // 1.0M
  // NOTE: pay_a top = payB + 2.0M u64 = rank_g + 0.8M ushort < rank_h ✓

  hipMemsetAsync(d_ws, 0,
                 (size_t)205004 * sizeof(int) +
                     (size_t)(N_V + N_A) * EMB * sizeof(float),
                 stream);

  // degrees + ranks (single pass, 1 thread/edge)
  k_counts<<<NCH, 256, 0, stream>>>(c2v_t, a2v_t, a2v_s, deg_g, deg_h, deg_a,
                                    rank_g, rank_h, rank_a);
  k_allocs<<<2 * NBV + NBA, 256, 0, stream>>>(deg_g, off_g, deg_h, off_h,
                                              deg_a, off_a, ctr);
  // g side: packed payload fill -> edge MLP + reduce -> hacc
  k_fill_g<<<8 * NCH, 256, 0, stream>>>(c2v_t, c2v_s, ea_c2v, off_g, rank_g,
                                        payB);
  k_edge_v<0><<<E_C2V / 256, 256, 0, stream>>>(
      E_C2V, payB, x_v, x_c,
      gv_W1, gv_b1, gv_W2, gv_b2, fv_W1 + (size_t)D_V * EMB, deg_g, hacc);
  // h + a payloads in one pass (rank_g dead; payB free after edge_g)
  k_fill_ha<<<8 * NCHA, 256, 0, stream>>>(a2v_t, a2v_s, ea_a2v,
                                          off_h, rank_h, payB,
                                          off_a, rank_a, pay_a);
  k_edge_v<1><<<NCHA, 256, 0, stream>>>(
      E_A2V, payB, x_v, x_a,
      hv_W1, hv_b1, hv_W2, hv_b2, fv_W1 + (size_t)(D_V + EMB) * EMB, deg_h,
      hacc);
  // f_v in-place: hacc rows become fv rows
  k_node_fv<<<(N_V + 255) / 256, 256, 0, stream>>>(
      x_v, hacc, fv_W1, fv_b1, fv_W2, fv_b2);
  // a side edge MLP + reduce -> hacc_a
  k_edge_a<<<NCHA, 256, 0, stream>>>(
      pay_a, x_a, hacc,
      ga_W1, ga_b1, ga_W2, ga_b2, fa_W1 + (size_t)D_A * EMB, deg_a, hacc_a);
  // f_a -> out
  k_node_fa<<<(N_A + 255) / 256, 256, 0, stream>>>(
      x_a, hacc_a, fa_W1, fa_b1, fa_W2, fa_b2, (float*)d_out);
}

// Round 17
// 670.804 us; speedup vs baseline: 1.2815x; 1.0519x over previous
//
#include <hip/hip_runtime.h>

// Problem constants (from reference)
#define N_C 50000
#define N_V 100000
#define N_A 5000
#define E_C2V 1600000
#define E_A2V 1000000
#define D_V 13
#define D_C 14
#define D_A 14
#define EMB 32

// Residue-major node-index permutation (XCD-local CSR lines; round 8).
#define PV(t) (((t) >> 3) + ((t)&7) * (N_V / 8))  // N_V/8 = 12500
#define PA(t) (((t) >> 3) + ((t)&7) * (N_A / 8))  // N_A/8 = 625
#define NCH (E_C2V / 256)                         // 6250 chunks, exact
#define NCHA ((E_A2V + 255) / 256)                // 3907
#define RBLK 16384                                // edges per k_rank_a block

typedef float v2f __attribute__((ext_vector_type(2)));
typedef unsigned long long u64;
typedef unsigned char u8;

// Pack (key_hi:17b, key_lo:16b, ea as bf16 RNE) into one u64.
__device__ __forceinline__ u64 pack_edge(int hi, int lo, float ea) {
  unsigned b = __float_as_uint(ea);
  b += 0x7FFFu + ((b >> 16) & 1u);  // round-to-nearest-even to bf16
  return ((u64)(unsigned)hi << 32) | ((u64)(unsigned)(lo & 0xFFFF) << 16) |
         (u64)(b >> 16);
}

// Pack two floats to bf16 pair (RNE) in one uint: low=a, high=b.
__device__ __forceinline__ unsigned bf16pk(float a, float b) {
  unsigned ua = __float_as_uint(a);
  ua += 0x7FFFu + ((ua >> 16) & 1u);
  unsigned ub = __float_as_uint(b);
  ub += 0x7FFFu + ((ub >> 16) & 1u);
  return (ua >> 16) | (ub & 0xFFFF0000u);
}

// h2[j] (16 x float2 = 32 channels) += v * Wrow[2j..2j+1] via v_pk_fma_f32.
__device__ __forceinline__ void accrow2(v2f* __restrict__ h, float v,
                                        const float* __restrict__ Wrow) {
  const v2f* w = (const v2f*)Wrow;
  v2f vv = {v, v};
#pragma unroll
  for (int j = 0; j < 16; ++j) h[j] = __builtin_elementwise_fma(vv, w[j], h[j]);
}

__device__ __forceinline__ void relu2(v2f* __restrict__ h) {
  v2f z = {0.0f, 0.0f};
#pragma unroll
  for (int j = 0; j < 16; ++j) h[j] = __builtin_elementwise_max(h[j], z);
}

__device__ __forceinline__ void layer2(v2f* __restrict__ o2,
                                       const v2f* __restrict__ h,
                                       const float* __restrict__ W2,
                                       const float* __restrict__ b2) {
  const v2f* b = (const v2f*)b2;
#pragma unroll
  for (int j = 0; j < 16; ++j) o2[j] = b[j];
#pragma unroll
  for (int k = 0; k < EMB; ++k) {
    float hk = h[k >> 1][k & 1];
    accrow2(o2, hk, W2 + k * EMB);
  }
}

// -------- g/h degree histograms + per-edge rank capture (atomicAdd return).
// Ranks fit u8: deg ~ Poisson(16)/Poisson(10), P(deg >= 256) ~ 0.
__global__ __launch_bounds__(256) void k_counts(
    const int* __restrict__ c2v_t, const int* __restrict__ a2v_t,
    int* __restrict__ deg_g, int* __restrict__ deg_h,
    u8* __restrict__ rank_g, u8* __restrict__ rank_h) {
  int e = blockIdx.x * 256 + threadIdx.x;  // grid exact: E_C2V % 256 == 0
  int t = c2v_t[e];
  rank_g[e] = (u8)atomicAdd(&deg_g[PV(t)], 1);
  if (e < E_A2V) {
    int th = a2v_t[e];
    rank_h[e] = (u8)atomicAdd(&deg_h[PV(th)], 1);
  }
}

// -------- a-side rank via block-local LDS histogram (N_A = 5000 bins fits).
// Fabric atomics: one per nonzero bin per block (~0.3M) instead of one per
// edge (1.0M). Local rank via LDS atomic re-insert (any unique local order
// is valid: slot alloc is order-agnostic).
__global__ __launch_bounds__(256) void k_rank_a(
    const int* __restrict__ a2v_s, int* __restrict__ deg_a,
    unsigned short* __restrict__ rank_a) {
  __shared__ unsigned int hist[N_A];  // 20 KB
  __shared__ int base[N_A];           // 20 KB
  int e0 = blockIdx.x * RBLK;
  for (int b = threadIdx.x; b < N_A; b += 256) hist[b] = 0;
  __syncthreads();
  // pass 1: local counts
  for (int i = threadIdx.x; i < RBLK; i += 256) {
    int e = e0 + i;
    if (e < E_A2V) atomicAdd(&hist[a2v_s[e]], 1u);
  }
  __syncthreads();
  // pass 2: one fabric atomic per nonzero bin -> block's base in node range
  for (int b = threadIdx.x; b < N_A; b += 256) {
    unsigned c = hist[b];
    if (c) base[b] = atomicAdd(&deg_a[PA(b)], (int)c);
    hist[b] = 0;  // re-zero for pass 3
  }
  __syncthreads();
  // pass 3: re-insert for unique local rank
  for (int i = threadIdx.x; i < RBLK; i += 256) {
    int e = e0 + i;
    if (e < E_A2V) {
      int a = a2v_s[e];
      unsigned lr = atomicAdd(&hist[a], 1u);
      rank_a[e] = (unsigned short)(base[a] + (int)lr);
    }
  }
}

// -------- merged slot allocation (order-agnostic disjoint ranges)
#define NBV ((N_V + 255) / 256)  // 391
#define NBA ((N_A + 255) / 256)  // 20
__global__ __launch_bounds__(256) void k_allocs(
    const int* __restrict__ deg_g, int* __restrict__ off_g,
    const int* __restrict__ deg_h, int* __restrict__ off_h,
    const int* __restrict__ deg_a, int* __restrict__ off_a,
    int* __restrict__ ctr) {
  const int* deg;
  int* off;
  int* c;
  int i, n;
  if (blockIdx.x < NBV) {
    i = blockIdx.x * 256 + threadIdx.x;
    deg = deg_g; off = off_g; c = ctr + 0; n = N_V;
  } else if (blockIdx.x < 2 * NBV) {
    i = (blockIdx.x - NBV) * 256 + threadIdx.x;
    deg = deg_h; off = off_h; c = ctr + 1; n = N_V;
  } else {
    i = (blockIdx.x - 2 * NBV) * 256 + threadIdx.x;
    deg = deg_a; off = off_a; c = ctr + 2; n = N_A;
  }
  int lane = threadIdx.x & 63;
  int d = (i < n) ? deg[i] : 0;
  int v = d;
#pragma unroll
  for (int s = 1; s < 64; s <<= 1) {
    int t = __shfl_up(v, s, 64);
    if (lane >= s) v += t;
  }
  int total = __shfl(v, 63, 64);
  int base = 0;
  if (lane == 63) base = atomicAdd(c, total);
  base = __shfl(base, 63, 64);
  if (i < n) off[i] = base + v - d;
}

// -------- atomic-free payload fills: ONE packed 8-B scattered store/edge.
// pos = off[key] + rank[e]; residue-partitioned so scatter lines stay
// XCD-local (round 8).
__global__ __launch_bounds__(256) void k_fill_g(
    const int* __restrict__ c2v_t, const int* __restrict__ c2v_s,
    const float* __restrict__ ea, const int* __restrict__ off_g,
    const u8* __restrict__ rank_g, u64* __restrict__ pay) {
  int res = blockIdx.x & 7;
  int e = (blockIdx.x >> 3) * 256 + threadIdx.x;  // 8*NCH grid, exact
  int t = c2v_t[e];
  if ((t & 7) == res) {
    int pos = off_g[PV(t)] + (int)rank_g[e];
    pay[pos] = pack_edge(t, c2v_s[e], ea[e]);  // s < 50000 < 2^16
  }
}

// h and a fills merged: one pass over the a2v edge list fills both payloads.
__global__ __launch_bounds__(256) void k_fill_ha(
    const int* __restrict__ a2v_t, const int* __restrict__ a2v_s,
    const float* __restrict__ ea,
    const int* __restrict__ off_h, const u8* __restrict__ rank_h,
    u64* __restrict__ pay_h,
    const int* __restrict__ off_a, const unsigned short* __restrict__ rank_a,
    u64* __restrict__ pay_a) {
  int res = blockIdx.x & 7;
  int e = (blockIdx.x >> 3) * 256 + threadIdx.x;
  if (e >= E_A2V) return;
  int t = a2v_t[e];
  int a = a2v_s[e];
  if ((t & 7) == res) {
    int pos = off_h[PV(t)] + (int)rank_h[e];
    pay_h[pos] = pack_edge(t, a, ea[e]);  // s < 5000
  }
  if ((a & 7) == res) {
    int pos = off_a[PA(a)] + (int)rank_a[e];
    pay_a[pos] = pack_edge(t, a, ea[e]);  // hi=t (17b), lo=a (<5000)
  }
}

// -------- edge-parallel v-side edge MLP (FIN=28, packed) + per-wave LDS
// segmented reduce (HALF-SPLIT: lanes 0-31 scan rows 0-31, lanes 32-63 scan
// rows 32-63 concurrently; 32 serial iters instead of 64; straddle segments
// become two boundary atomics -- sums still correct) + projection -> hacc.
template <int ADDMODE>
__global__ __launch_bounds__(256) void k_edge_v(
    int E, const u64* __restrict__ pay,
    const float* __restrict__ x_t,   // variable-node feats (13)
    const float* __restrict__ x_s,   // source feats (14), rows 8B-aligned
    const float* __restrict__ W1, const float* __restrict__ b1,
    const float* __restrict__ W2, const float* __restrict__ b2,
    const float* __restrict__ Wp,    // fW1 + (13 or 45)*32 projection slice
    const int* __restrict__ deg,     // residue-major indexed
    float* __restrict__ hacc) {
  __shared__ unsigned short vals[4][64][34];  // bf16; 4B-aligned rows
  __shared__ int nidl[4][64];
  __shared__ float segx[4][2][32];
  int wv = threadIdx.x >> 6;
  int lane = threadIdx.x & 63;
  int slot = blockIdx.x * 256 + threadIdx.x;
  if ((slot & ~63) >= E) return;  // wave-uniform exit (E % 64 == 0)

  u64 p = pay[slot];
  int t = (int)(p >> 32);
  int s = (int)((p >> 16) & 0xFFFFull);
  float eav = __uint_as_float((unsigned)(p & 0xFFFFull) << 16);
  const float* xt = x_t + (size_t)t * D_V;

  v2f h[16];
  const v2f* b1v = (const v2f*)b1;
#pragma unroll
  for (int j = 0; j < 16; ++j) h[j] = b1v[j];
#pragma unroll
  for (int i = 0; i < D_V; ++i) accrow2(h, xt[i], W1 + i * EMB);
  const float2* xs2 = (const float2*)(x_s + (size_t)s * D_C);
#pragma unroll
  for (int i = 0; i < 7; ++i) {
    float2 wv2 = xs2[i];
    accrow2(h, wv2.x, W1 + (D_V + 2 * i) * EMB);
    accrow2(h, wv2.y, W1 + (D_V + 2 * i + 1) * EMB);
  }
  accrow2(h, eav, W1 + 27 * EMB);
  relu2(h);
  v2f o2[16];
  layer2(o2, h, W2, b2);
  relu2(o2);
  {
    unsigned* vr = (unsigned*)&vals[wv][lane][0];  // 68*lane: 4B-aligned
#pragma unroll
    for (int j = 0; j < 16; ++j) vr[j] = bf16pk(o2[j].x, o2[j].y);
  }
  nidl[wv][lane] = t;
  // wave-synchronous half-split segmented reduce (all 64 lanes active)
  {
    int half = lane >> 5;
    int j = lane & 31;
    float acc = 0.0f;
    int r0 = 0;
    for (int r = 0; r < 32; ++r) {
      int row = half * 32 + r;
      acc += __uint_as_float((unsigned)vals[wv][row][j] << 16);
      int cur = nidl[wv][row];
      bool flush = (r == 31) || (nidl[wv][row + 1] != cur);
      if (flush) {  // per-lane; all addressing lane-local, halves may pair
        float inv = 1.0f / fmaxf((float)deg[PV(cur)], 1.0f);
        segx[wv][half][j] = acc * inv;
        float out = 0.0f;
#pragma unroll
        for (int k = 0; k < EMB; ++k)
          out = fmaf(segx[wv][half][k], Wp[k * EMB + j], out);
        float* dst = &hacc[(size_t)cur * EMB + j];
        bool interior = (r0 > 0) && (r < 31);  // node's full range in half
        if (interior) {
          if (ADDMODE) out += *dst;
          *dst = out;
        } else {
          atomicAdd(dst, out);
        }
        acc = 0.0f;
        r0 = r + 1;
      }
    }
  }
}

// -------- edge-parallel a-side g_a MLP (FIN=47, packed) + half-split reduce
__global__ __launch_bounds__(256) void k_edge_a(
    const u64* __restrict__ pay,
    const float* __restrict__ xa_g, const float* __restrict__ fv,
    const float* __restrict__ W1, const float* __restrict__ b1,
    const float* __restrict__ W2, const float* __restrict__ b2,
    const float* __restrict__ Wp,   // fa_W1 + 14*32
    const int* __restrict__ deg,
    float* __restrict__ hacc_a) {
  __shared__ unsigned short vals[4][64][34];
  __shared__ int nidl[4][64];
  __shared__ float segx[4][2][32];
  int wv = threadIdx.x >> 6;
  int lane = threadIdx.x & 63;
  int slot = blockIdx.x * 256 + threadIdx.x;
  if ((slot & ~63) >= E_A2V) return;

  u64 p = pay[slot];
  int t = (int)(p >> 32);
  int a = (int)((p >> 16) & 0xFFFFull);
  float eav = __uint_as_float((unsigned)(p & 0xFFFFull) << 16);

  v2f h[16];
  const v2f* b1v = (const v2f*)b1;
#pragma unroll
  for (int j = 0; j < 16; ++j) h[j] = b1v[j];
  const float2* ps2 = (const float2*)(xa_g + (size_t)a * D_A);
#pragma unroll
  for (int i = 0; i < 7; ++i) {
    float2 wv2 = ps2[i];
    accrow2(h, wv2.x, W1 + (2 * i) * EMB);
    accrow2(h, wv2.y, W1 + (2 * i + 1) * EMB);
  }
  const float4* pf = (const float4*)(fv + (size_t)t * EMB);
#pragma unroll
  for (int q = 0; q < 8; ++q) {
    float4 f = pf[q];
    accrow2(h, f.x, W1 + (D_A + 4 * q) * EMB);
    accrow2(h, f.y, W1 + (D_A + 4 * q + 1) * EMB);
    accrow2(h, f.z, W1 + (D_A + 4 * q + 2) * EMB);
    accrow2(h, f.w, W1 + (D_A + 4 * q + 3) * EMB);
  }
  accrow2(h, eav, W1 + 46 * EMB);
  relu2(h);
  v2f o2[16];
  layer2(o2, h, W2, b2);
  relu2(o2);
  {
    unsigned* vr = (unsigned*)&vals[wv][lane][0];
#pragma unroll
    for (int j = 0; j < 16; ++j) vr[j] = bf16pk(o2[j].x, o2[j].y);
  }
  nidl[wv][lane] = a;
  {
    int half = lane >> 5;
    int j = lane & 31;
    float acc = 0.0f;
    int r0 = 0;
    for (int r = 0; r < 32; ++r) {
      int row = half * 32 + r;
      acc += __uint_as_float((unsigned)vals[wv][row][j] << 16);
      int cur = nidl[wv][row];
      bool flush = (r == 31) || (nidl[wv][row + 1] != cur);
      if (flush) {
        float inv = 1.0f / fmaxf((float)deg[PA(cur)], 1.0f);
        segx[wv][half][j] = acc * inv;
        float out = 0.0f;
#pragma unroll
        for (int k = 0; k < EMB; ++k)
          out = fmaf(segx[wv][half][k], Wp[k * EMB + j], out);
        float* dst = &hacc_a[(size_t)cur * EMB + j];
        bool interior = (r0 > 0) && (r < 31);
        if (interior) {
          *dst = out;  // sole writer (zeroed buffer, single dispatch)
        } else {
          atomicAdd(dst, out);
        }
        acc = 0.0f;
        r0 = r + 1;
      }
    }
  }
}

// -------- f_v node MLP, IN-PLACE on hacc (same thread reads+writes row v).
__global__ __launch_bounds__(256) void k_node_fv(
    const float* __restrict__ xv_g, float* hf,
    const float* __restrict__ fW1, const float* __restrict__ fb1,
    const float* __restrict__ fW2, const float* __restrict__ fb2) {
  int v = blockIdx.x * blockDim.x + threadIdx.x;
  if (v >= N_V) return;
  v2f* row = (v2f*)(hf + (size_t)v * EMB);
  const v2f* bv = (const v2f*)fb1;
  v2f h[16];
#pragma unroll
  for (int j = 0; j < 16; ++j) h[j] = bv[j] + row[j];
  const float* pv = xv_g + (size_t)v * D_V;
#pragma unroll
  for (int i = 0; i < D_V; ++i) accrow2(h, pv[i], fW1 + i * EMB);
  relu2(h);
  v2f o2[16];
  layer2(o2, h, fW2, fb2);
  v2f z = {0.0f, 0.0f};
#pragma unroll
  for (int j = 0; j < 16; ++j)
    row[j] = __builtin_elementwise_max(o2[j], z);  // relu_out (+idempotent)
}

// -------- f_a node MLP on pre-accumulated hidden -> d_out (packed)
__global__ __launch_bounds__(256) void k_node_fa(
    const float* __restrict__ xa, const float* __restrict__ hacc_a,
    const float* __restrict__ W1, const float* __restrict__ b1,
    const float* __restrict__ W2, const float* __restrict__ b2,
    float* __restrict__ out) {
  int a = blockIdx.x * blockDim.x + threadIdx.x;
  if (a >= N_A) return;
  const v2f* hr = (const v2f*)(hacc_a + (size_t)a * EMB);
  const v2f* bv = (const v2f*)b1;
  v2f h[16];
#pragma unroll
  for (int j = 0; j < 16; ++j) h[j] = bv[j] + hr[j];
  const float2* pa = (const float2*)(xa + (size_t)a * D_A);
#pragma unroll
  for (int i = 0; i < 7; ++i) {
    float2 w = pa[i];
    accrow2(h, w.x, W1 + (2 * i) * EMB);
    accrow2(h, w.y, W1 + (2 * i + 1) * EMB);
  }
  relu2(h);
  v2f o2[16];
  layer2(o2, h, W2, b2);
  v2f z = {0.0f, 0.0f};
  v2f* dst = (v2f*)(out + (size_t)a * EMB);
#pragma unroll
  for (int j = 0; j < 16; ++j)
    dst[j] = __builtin_elementwise_max(o2[j], z);
}

extern "C" void kernel_launch(void* const* d_in, const int* in_sizes, int n_in,
                              void* d_out, int out_size, void* d_ws, size_t ws_size,
                              hipStream_t stream) {
  const float* x_c = (const float*)d_in[0];
  const float* x_v = (const float*)d_in[1];
  const float* x_a = (const float*)d_in[2];
  const int* c2v_s = (const int*)d_in[3];
  const int* c2v_t = (const int*)d_in[4];
  const int* a2v_s = (const int*)d_in[5];
  const int* a2v_t = (const int*)d_in[6];
  const float* ea_c2v = (const float*)d_in[7];
  const float* ea_a2v = (const float*)d_in[8];
  const float* gv_W1 = (const float*)d_in[9];
  const float* gv_b1 = (const float*)d_in[10];
  const float* gv_W2 = (const float*)d_in[11];
  const float* gv_b2 = (const float*)d_in[12];
  const float* hv_W1 = (const float*)d_in[13];
  const float* hv_b1 = (const float*)d_in[14];
  const float* hv_W2 = (const float*)d_in[15];
  const float* hv_b2 = (const float*)d_in[16];
  const float* fv_W1 = (const float*)d_in[17];
  const float* fv_b1 = (const float*)d_in[18];
  const float* fv_W2 = (const float*)d_in[19];
  const float* fv_b2 = (const float*)d_in[20];
  const float* ga_W1 = (const float*)d_in[21];
  const float* ga_b1 = (const float*)d_in[22];
  const float* ga_W2 = (const float*)d_in[23];
  const float* ga_b2 = (const float*)d_in[24];
  const float* fa_W1 = (const float*)d_in[25];
  const float* fa_b1 = (const float*)d_in[26];
  const float* fa_W2 = (const float*)d_in[27];
  const float* fa_b2 = (const float*)d_in[28];

  // ---- workspace layout: ~35.7 MB (proven envelope ~39.9 MB) ----
  int* ip = (int*)d_ws;
  int* deg_g = ip;                  // 100000
  int* deg_h = deg_g + N_V;         // 100000
  int* deg_a = deg_h + N_V;         // 5000
  int* ctr = deg_a + N_A;           // 4
  float* hacc = (float*)(ctr + 4);              // N_V*32 (becomes fv in-place)
  float* hacc_a = hacc + (size_t)N_V * EMB;     // N_A*32
  int* off_g = (int*)(hacc_a + (size_t)N_A * EMB);  // 100000
  int* off_h = off_g + N_V;                         // 100000
  int* off_a = off_h + N_V;                         // 5000
  // Payload region P: 2.0M u64 (16 MB), byte offset 15,080,016 (8B-aligned).
  //   phase g: pay_g = P[0..1.6M)
  //   phase h/a: pay_h = P[0..1.0M), pay_a = P[1.0M..2.0M)
  u64* P = (u64*)(off_a + N_A);
  u64* pay_a = P + E_A2V;
  // rank arrays after P (u8 for g/h, u16 for a)
  u8* rank_g = (u8*)(P + 2 * E_A2V);       // 1.6M B
  u8* rank_h = rank_g + E_C2V;             // 1.0M B
  unsigned short* rank_a = (unsigned short*)(rank_h + E_A2V);  // 2.0M B (even off)

  hipMemsetAsync(d_ws, 0,
                 (size_t)205004 * sizeof(int) +
                     (size_t)(N_V + N_A) * EMB * sizeof(float),
                 stream);

  // g/h degrees + u8 ranks (fabric atomics: 2.6M)
  k_counts<<<NCH, 256, 0, stream>>>(c2v_t, a2v_t, deg_g, deg_h, rank_g, rank_h);
  // a-side degree + rank via LDS histogram (fabric atomics: ~0.3M)
  k_rank_a<<<(E_A2V + RBLK - 1) / RBLK, 256, 0, stream>>>(a2v_s, deg_a, rank_a);
  k_allocs<<<2 * NBV + NBA, 256, 0, stream>>>(deg_g, off_g, deg_h, off_h,
                                              deg_a, off_a, ctr);
  // g side: packed payload fill -> edge MLP + reduce -> hacc
  k_fill_g<<<8 * NCH, 256, 0, stream>>>(c2v_t, c2v_s, ea_c2v, off_g, rank_g, P);
  k_edge_v<0><<<E_C2V / 256, 256, 0, stream>>>(
      E_C2V, P, x_v, x_c,
      gv_W1, gv_b1, gv_W2, gv_b2, fv_W1 + (size_t)D_V * EMB, deg_g, hacc);
  // h + a payloads in one pass (P free after edge_g)
  k_fill_ha<<<8 * NCHA, 256, 0, stream>>>(a2v_t, a2v_s, ea_a2v,
                                          off_h, rank_h, P,
                                          off_a, rank_a, pay_a);
  k_edge_v<1><<<NCHA, 256, 0, stream>>>(
      E_A2V, P, x_v, x_a,
      hv_W1, hv_b1, hv_W2, hv_b2, fv_W1 + (size_t)(D_V + EMB) * EMB, deg_h,
      hacc);
  // f_v in-place: hacc rows become fv rows
  k_node_fv<<<(N_V + 255) / 256, 256, 0, stream>>>(
      x_v, hacc, fv_W1, fv_b1, fv_W2, fv_b2);
  // a side edge MLP + reduce -> hacc_a
  k_edge_a<<<NCHA, 256, 0, stream>>>(
      pay_a, x_a, hacc,
      ga_W1, ga_b1, ga_W2, ga_b2, fa_W1 + (size_t)D_A * EMB, deg_a, hacc_a);
  // f_a -> out
  k_node_fa<<<(N_A + 255) / 256, 256, 0, stream>>>(
      x_a, hacc_a, fa_W1, fa_b1, fa_W2, fa_b2, (float*)d_out);
}

// Round 18
// 613.651 us; speedup vs baseline: 1.4008x; 1.0931x over previous
//
#include <hip/hip_runtime.h>

// Problem constants (from reference)
#define N_C 50000
#define N_V 100000
#define N_A 5000
#define E_C2V 1600000
#define E_A2V 1000000
#define D_V 13
#define D_C 14
#define D_A 14
#define EMB 32

// Residue-major node-index permutation (XCD-local CSR lines; round 8).
#define PV(t) (((t) >> 3) + ((t)&7) * (N_V / 8))  // N_V/8 = 12500
#define PA(t) (((t) >> 3) + ((t)&7) * (N_A / 8))  // N_A/8 = 625
#define NCH (E_C2V / 256)                         // 6250 chunks, exact
#define NCHA ((E_A2V + 255) / 256)                // 3907
#define RBLK 16384                                // edges per k_rank_a block

typedef float v2f __attribute__((ext_vector_type(2)));
typedef float f32x4 __attribute__((ext_vector_type(4)));
typedef short bf16x8 __attribute__((ext_vector_type(8)));
typedef unsigned long long u64;
typedef unsigned char u8;

// Pack (key_hi:17b, key_lo:16b, ea as bf16 RNE) into one u64.
__device__ __forceinline__ u64 pack_edge(int hi, int lo, float ea) {
  unsigned b = __float_as_uint(ea);
  b += 0x7FFFu + ((b >> 16) & 1u);  // round-to-nearest-even to bf16
  return ((u64)(unsigned)hi << 32) | ((u64)(unsigned)(lo & 0xFFFF) << 16) |
         (u64)(b >> 16);
}

// bf16 RNE of one float (u16).
__device__ __forceinline__ unsigned short bf16r(float x) {
  unsigned u = __float_as_uint(x);
  u += 0x7FFFu + ((u >> 16) & 1u);
  return (unsigned short)(u >> 16);
}

// Pack two floats to bf16 pair (RNE) in one uint: low=a, high=b.
__device__ __forceinline__ unsigned bf16pk(float a, float b) {
  unsigned ua = __float_as_uint(a);
  ua += 0x7FFFu + ((ua >> 16) & 1u);
  unsigned ub = __float_as_uint(b);
  ub += 0x7FFFu + ((ub >> 16) & 1u);
  return (ua >> 16) | (ub & 0xFFFF0000u);
}

// h2[j] (16 x float2 = 32 channels) += v * Wrow[2j..2j+1] via v_pk_fma_f32.
__device__ __forceinline__ void accrow2(v2f* __restrict__ h, float v,
                                        const float* __restrict__ Wrow) {
  const v2f* w = (const v2f*)Wrow;
  v2f vv = {v, v};
#pragma unroll
  for (int j = 0; j < 16; ++j) h[j] = __builtin_elementwise_fma(vv, w[j], h[j]);
}

__device__ __forceinline__ void relu2(v2f* __restrict__ h) {
  v2f z = {0.0f, 0.0f};
#pragma unroll
  for (int j = 0; j < 16; ++j) h[j] = __builtin_elementwise_max(h[j], z);
}

__device__ __forceinline__ void layer2(v2f* __restrict__ o2,
                                       const v2f* __restrict__ h,
                                       const float* __restrict__ W2,
                                       const float* __restrict__ b2) {
  const v2f* b = (const v2f*)b2;
#pragma unroll
  for (int j = 0; j < 16; ++j) o2[j] = b[j];
#pragma unroll
  for (int k = 0; k < EMB; ++k) {
    float hk = h[k >> 1][k & 1];
    accrow2(o2, hk, W2 + k * EMB);
  }
}

// -------- MFMA layer2: vals_wv holds relu'd h as bf16 (u32-pair rows of
// stride 18 u32 = 72 B). Computes relu(h x W2 + b2) with 8x
// mfma_f32_16x16x32_bf16 (M=64 edges, N=32, K=32) and overwrites vals_wv
// with the bf16 outputs in [edge][ch] layout (u16 rows, stride 36).
// All A-fragments are loaded BEFORE any writeback (wave-lockstep safe).
// Layouts (guide-verified): A[m=lane&15][k=quad*8+j]; B[k=quad*8+j][n=lane&15];
// C col=lane&15, row=quad*4+reg.
__device__ __forceinline__ void layer2_mfma(
    unsigned short* __restrict__ vals_wv, int lane,
    const float* __restrict__ W2, const float* __restrict__ b2) {
  int q = lane >> 4;
  int n = lane & 15;
  // B fragments (ni = 0,1): column n+16*ni, k rows q*8..q*8+7 (L1-hot)
  bf16x8 bfr[2];
#pragma unroll
  for (int ni = 0; ni < 2; ++ni) {
#pragma unroll
    for (int j = 0; j < 8; ++j)
      bfr[ni][j] = (short)bf16r(W2[(q * 8 + j) * EMB + ni * 16 + n]);
  }
  // A fragments (mi = 0..3): row m = mi*16+n, 8 bf16 at u32 idx q*4..q*4+3
  union {
    u64 d[2];
    bf16x8 v;
  } afr[4];
#pragma unroll
  for (int mi = 0; mi < 4; ++mi) {
    const u64* rp =
        (const u64*)((const char*)vals_wv + (size_t)(mi * 16 + n) * 72 + q * 16);
    afr[mi].d[0] = rp[0];
    afr[mi].d[1] = rp[1];
  }
  float bb0 = b2[n], bb1 = b2[16 + n];
#pragma unroll
  for (int mi = 0; mi < 4; ++mi) {
#pragma unroll
    for (int ni = 0; ni < 2; ++ni) {
      f32x4 c = {0.f, 0.f, 0.f, 0.f};
      c = __builtin_amdgcn_mfma_f32_16x16x32_bf16(afr[mi].v, bfr[ni], c, 0, 0, 0);
      float bb = ni ? bb1 : bb0;
#pragma unroll
      for (int r = 0; r < 4; ++r) {
        float v = fmaxf(c[r] + bb, 0.0f);
        vals_wv[(size_t)(mi * 16 + q * 4 + r) * 36 + ni * 16 + n] = bf16r(v);
      }
    }
  }
}

// -------- g/h degree histograms + per-edge rank capture (atomicAdd return).
__global__ __launch_bounds__(256) void k_counts(
    const int* __restrict__ c2v_t, const int* __restrict__ a2v_t,
    int* __restrict__ deg_g, int* __restrict__ deg_h,
    u8* __restrict__ rank_g, u8* __restrict__ rank_h) {
  int e = blockIdx.x * 256 + threadIdx.x;  // grid exact: E_C2V % 256 == 0
  int t = c2v_t[e];
  rank_g[e] = (u8)atomicAdd(&deg_g[PV(t)], 1);
  if (e < E_A2V) {
    int th = a2v_t[e];
    rank_h[e] = (u8)atomicAdd(&deg_h[PV(th)], 1);
  }
}

// -------- a-side rank via block-local LDS histogram (N_A = 5000 bins).
__global__ __launch_bounds__(256) void k_rank_a(
    const int* __restrict__ a2v_s, int* __restrict__ deg_a,
    unsigned short* __restrict__ rank_a) {
  __shared__ unsigned int hist[N_A];
  __shared__ int base[N_A];
  int e0 = blockIdx.x * RBLK;
  for (int b = threadIdx.x; b < N_A; b += 256) hist[b] = 0;
  __syncthreads();
  for (int i = threadIdx.x; i < RBLK; i += 256) {
    int e = e0 + i;
    if (e < E_A2V) atomicAdd(&hist[a2v_s[e]], 1u);
  }
  __syncthreads();
  for (int b = threadIdx.x; b < N_A; b += 256) {
    unsigned c = hist[b];
    if (c) base[b] = atomicAdd(&deg_a[PA(b)], (int)c);
    hist[b] = 0;
  }
  __syncthreads();
  for (int i = threadIdx.x; i < RBLK; i += 256) {
    int e = e0 + i;
    if (e < E_A2V) {
      int a = a2v_s[e];
      unsigned lr = atomicAdd(&hist[a], 1u);
      rank_a[e] = (unsigned short)(base[a] + (int)lr);
    }
  }
}

// -------- merged slot allocation (order-agnostic disjoint ranges)
#define NBV ((N_V + 255) / 256)  // 391
#define NBA ((N_A + 255) / 256)  // 20
__global__ __launch_bounds__(256) void k_allocs(
    const int* __restrict__ deg_g, int* __restrict__ off_g,
    const int* __restrict__ deg_h, int* __restrict__ off_h,
    const int* __restrict__ deg_a, int* __restrict__ off_a,
    int* __restrict__ ctr) {
  const int* deg;
  int* off;
  int* c;
  int i, n;
  if (blockIdx.x < NBV) {
    i = blockIdx.x * 256 + threadIdx.x;
    deg = deg_g; off = off_g; c = ctr + 0; n = N_V;
  } else if (blockIdx.x < 2 * NBV) {
    i = (blockIdx.x - NBV) * 256 + threadIdx.x;
    deg = deg_h; off = off_h; c = ctr + 1; n = N_V;
  } else {
    i = (blockIdx.x - 2 * NBV) * 256 + threadIdx.x;
    deg = deg_a; off = off_a; c = ctr + 2; n = N_A;
  }
  int lane = threadIdx.x & 63;
  int d = (i < n) ? deg[i] : 0;
  int v = d;
#pragma unroll
  for (int s = 1; s < 64; s <<= 1) {
    int t = __shfl_up(v, s, 64);
    if (lane >= s) v += t;
  }
  int total = __shfl(v, 63, 64);
  int base = 0;
  if (lane == 63) base = atomicAdd(c, total);
  base = __shfl(base, 63, 64);
  if (i < n) off[i] = base + v - d;
}

// -------- atomic-free payload fills (one 8-B scattered store/edge).
__global__ __launch_bounds__(256) void k_fill_g(
    const int* __restrict__ c2v_t, const int* __restrict__ c2v_s,
    const float* __restrict__ ea, const int* __restrict__ off_g,
    const u8* __restrict__ rank_g, u64* __restrict__ pay) {
  int res = blockIdx.x & 7;
  int e = (blockIdx.x >> 3) * 256 + threadIdx.x;  // 8*NCH grid, exact
  int t = c2v_t[e];
  if ((t & 7) == res) {
    int pos = off_g[PV(t)] + (int)rank_g[e];
    pay[pos] = pack_edge(t, c2v_s[e], ea[e]);  // s < 50000 < 2^16
  }
}

__global__ __launch_bounds__(256) void k_fill_ha(
    const int* __restrict__ a2v_t, const int* __restrict__ a2v_s,
    const float* __restrict__ ea,
    const int* __restrict__ off_h, const u8* __restrict__ rank_h,
    u64* __restrict__ pay_h,
    const int* __restrict__ off_a, const unsigned short* __restrict__ rank_a,
    u64* __restrict__ pay_a) {
  int res = blockIdx.x & 7;
  int e = (blockIdx.x >> 3) * 256 + threadIdx.x;
  if (e >= E_A2V) return;
  int t = a2v_t[e];
  int a = a2v_s[e];
  if ((t & 7) == res) {
    int pos = off_h[PV(t)] + (int)rank_h[e];
    pay_h[pos] = pack_edge(t, a, ea[e]);
  }
  if ((a & 7) == res) {
    int pos = off_a[PA(a)] + (int)rank_a[e];
    pay_a[pos] = pack_edge(t, a, ea[e]);
  }
}

// -------- edge-parallel v-side edge MLP: layer1 packed-fp32, layer2 MFMA,
// half-split LDS segmented reduce + projection -> hacc.
template <int ADDMODE>
__global__ __launch_bounds__(256) void k_edge_v(
    int E, const u64* __restrict__ pay,
    const float* __restrict__ x_t,   // variable-node feats (13)
    const float* __restrict__ x_s,   // source feats (14), rows 8B-aligned
    const float* __restrict__ W1, const float* __restrict__ b1,
    const float* __restrict__ W2, const float* __restrict__ b2,
    const float* __restrict__ Wp,    // fW1 + (13 or 45)*32 projection slice
    const int* __restrict__ deg,     // residue-major indexed
    float* __restrict__ hacc) {
  // vals: first holds bf16 h (u32-pair rows, stride 18 u32 = 72 B), then
  // overwritten by layer2_mfma with bf16 outputs ([edge][ch], u16 stride 36).
  __shared__ __align__(16) unsigned short vals[4][64][36];
  __shared__ int nidl[4][64];
  __shared__ float segx[4][2][32];
  int wv = threadIdx.x >> 6;
  int lane = threadIdx.x & 63;
  int slot = blockIdx.x * 256 + threadIdx.x;
  if ((slot & ~63) >= E) return;  // wave-uniform exit (E % 64 == 0)

  u64 p = pay[slot];
  int t = (int)(p >> 32);
  int s = (int)((p >> 16) & 0xFFFFull);
  float eav = __uint_as_float((unsigned)(p & 0xFFFFull) << 16);
  const float* xt = x_t + (size_t)t * D_V;

  v2f h[16];
  const v2f* b1v = (const v2f*)b1;
#pragma unroll
  for (int j = 0; j < 16; ++j) h[j] = b1v[j];
#pragma unroll
  for (int i = 0; i < D_V; ++i) accrow2(h, xt[i], W1 + i * EMB);
  const float2* xs2 = (const float2*)(x_s + (size_t)s * D_C);
#pragma unroll
  for (int i = 0; i < 7; ++i) {
    float2 wv2 = xs2[i];
    accrow2(h, wv2.x, W1 + (D_V + 2 * i) * EMB);
    accrow2(h, wv2.y, W1 + (D_V + 2 * i + 1) * EMB);
  }
  accrow2(h, eav, W1 + 27 * EMB);
  relu2(h);
  // stage relu'd h to LDS as bf16 pairs (row stride 18 u32)
  {
    unsigned* hm = (unsigned*)&vals[wv][0][0];
#pragma unroll
    for (int j = 0; j < 16; ++j)
      hm[lane * 18 + j] = bf16pk(h[j].x, h[j].y);
  }
  nidl[wv][lane] = t;
  // layer2 on the matrix pipe; outputs land back in vals as [edge][ch] bf16
  layer2_mfma(&vals[wv][0][0], lane, W2, b2);
  // wave-synchronous half-split segmented reduce (all 64 lanes active)
  {
    int half = lane >> 5;
    int j = lane & 31;
    float acc = 0.0f;
    int r0 = 0;
    for (int r = 0; r < 32; ++r) {
      int row = half * 32 + r;
      acc += __uint_as_float((unsigned)vals[wv][row][j] << 16);
      int cur = nidl[wv][row];
      bool flush = (r == 31) || (nidl[wv][row + 1] != cur);
      if (flush) {
        float inv = 1.0f / fmaxf((float)deg[PV(cur)], 1.0f);
        segx[wv][half][j] = acc * inv;
        float out = 0.0f;
#pragma unroll
        for (int k = 0; k < EMB; ++k)
          out = fmaf(segx[wv][half][k], Wp[k * EMB + j], out);
        float* dst = &hacc[(size_t)cur * EMB + j];
        bool interior = (r0 > 0) && (r < 31);  // node's full range in half
        if (interior) {
          if (ADDMODE) out += *dst;
          *dst = out;
        } else {
          atomicAdd(dst, out);
        }
        acc = 0.0f;
        r0 = r + 1;
      }
    }
  }
}

// -------- edge-parallel a-side g_a MLP (FIN=47): layer1 packed, layer2 MFMA
__global__ __launch_bounds__(256) void k_edge_a(
    const u64* __restrict__ pay,
    const float* __restrict__ xa_g, const float* __restrict__ fv,
    const float* __restrict__ W1, const float* __restrict__ b1,
    const float* __restrict__ W2, const float* __restrict__ b2,
    const float* __restrict__ Wp,   // fa_W1 + 14*32
    const int* __restrict__ deg,
    float* __restrict__ hacc_a) {
  __shared__ __align__(16) unsigned short vals[4][64][36];
  __shared__ int nidl[4][64];
  __shared__ float segx[4][2][32];
  int wv = threadIdx.x >> 6;
  int lane = threadIdx.x & 63;
  int slot = blockIdx.x * 256 + threadIdx.x;
  if ((slot & ~63) >= E_A2V) return;

  u64 p = pay[slot];
  int t = (int)(p >> 32);
  int a = (int)((p >> 16) & 0xFFFFull);
  float eav = __uint_as_float((unsigned)(p & 0xFFFFull) << 16);

  v2f h[16];
  const v2f* b1v = (const v2f*)b1;
#pragma unroll
  for (int j = 0; j < 16; ++j) h[j] = b1v[j];
  const float2* ps2 = (const float2*)(xa_g + (size_t)a * D_A);
#pragma unroll
  for (int i = 0; i < 7; ++i) {
    float2 wv2 = ps2[i];
    accrow2(h, wv2.x, W1 + (2 * i) * EMB);
    accrow2(h, wv2.y, W1 + (2 * i + 1) * EMB);
  }
  const float4* pf = (const float4*)(fv + (size_t)t * EMB);
#pragma unroll
  for (int q = 0; q < 8; ++q) {
    float4 f = pf[q];
    accrow2(h, f.x, W1 + (D_A + 4 * q) * EMB);
    accrow2(h, f.y, W1 + (D_A + 4 * q + 1) * EMB);
    accrow2(h, f.z, W1 + (D_A + 4 * q + 2) * EMB);
    accrow2(h, f.w, W1 + (D_A + 4 * q + 3) * EMB);
  }
  accrow2(h, eav, W1 + 46 * EMB);
  relu2(h);
  {
    unsigned* hm = (unsigned*)&vals[wv][0][0];
#pragma unroll
    for (int j = 0; j < 16; ++j)
      hm[lane * 18 + j] = bf16pk(h[j].x, h[j].y);
  }
  nidl[wv][lane] = a;
  layer2_mfma(&vals[wv][0][0], lane, W2, b2);
  {
    int half = lane >> 5;
    int j = lane & 31;
    float acc = 0.0f;
    int r0 = 0;
    for (int r = 0; r < 32; ++r) {
      int row = half * 32 + r;
      acc += __uint_as_float((unsigned)vals[wv][row][j] << 16);
      int cur = nidl[wv][row];
      bool flush = (r == 31) || (nidl[wv][row + 1] != cur);
      if (flush) {
        float inv = 1.0f / fmaxf((float)deg[PA(cur)], 1.0f);
        segx[wv][half][j] = acc * inv;
        float out = 0.0f;
#pragma unroll
        for (int k = 0; k < EMB; ++k)
          out = fmaf(segx[wv][half][k], Wp[k * EMB + j], out);
        float* dst = &hacc_a[(size_t)cur * EMB + j];
        bool interior = (r0 > 0) && (r < 31);
        if (interior) {
          *dst = out;  // sole writer (zeroed buffer, single dispatch)
        } else {
          atomicAdd(dst, out);
        }
        acc = 0.0f;
        r0 = r + 1;
      }
    }
  }
}

// -------- f_v node MLP, IN-PLACE on hacc (same thread reads+writes row v).
__global__ __launch_bounds__(256) void k_node_fv(
    const float* __restrict__ xv_g, float* hf,
    const float* __restrict__ fW1, const float* __restrict__ fb1,
    const float* __restrict__ fW2, const float* __restrict__ fb2) {
  int v = blockIdx.x * blockDim.x + threadIdx.x;
  if (v >= N_V) return;
  v2f* row = (v2f*)(hf + (size_t)v * EMB);
  const v2f* bv = (const v2f*)fb1;
  v2f h[16];
#pragma unroll
  for (int j = 0; j < 16; ++j) h[j] = bv[j] + row[j];
  const float* pv = xv_g + (size_t)v * D_V;
#pragma unroll
  for (int i = 0; i < D_V; ++i) accrow2(h, pv[i], fW1 + i * EMB);
  relu2(h);
  v2f o2[16];
  layer2(o2, h, fW2, fb2);
  v2f z = {0.0f, 0.0f};
#pragma unroll
  for (int j = 0; j < 16; ++j)
    row[j] = __builtin_elementwise_max(o2[j], z);  // relu_out (+idempotent)
}

// -------- f_a node MLP on pre-accumulated hidden -> d_out (packed)
__global__ __launch_bounds__(256) void k_node_fa(
    const float* __restrict__ xa, const float* __restrict__ hacc_a,
    const float* __restrict__ W1, const float* __restrict__ b1,
    const float* __restrict__ W2, const float* __restrict__ b2,
    float* __restrict__ out) {
  int a = blockIdx.x * blockDim.x + threadIdx.x;
  if (a >= N_A) return;
  const v2f* hr = (const v2f*)(hacc_a + (size_t)a * EMB);
  const v2f* bv = (const v2f*)b1;
  v2f h[16];
#pragma unroll
  for (int j = 0; j < 16; ++j) h[j] = bv[j] + hr[j];
  const float2* pa = (const float2*)(xa + (size_t)a * D_A);
#pragma unroll
  for (int i = 0; i < 7; ++i) {
    float2 w = pa[i];
    accrow2(h, w.x, W1 + (2 * i) * EMB);
    accrow2(h, w.y, W1 + (2 * i + 1) * EMB);
  }
  relu2(h);
  v2f o2[16];
  layer2(o2, h, W2, b2);
  v2f z = {0.0f, 0.0f};
  v2f* dst = (v2f*)(out + (size_t)a * EMB);
#pragma unroll
  for (int j = 0; j < 16; ++j)
    dst[j] = __builtin_elementwise_max(o2[j], z);
}

extern "C" void kernel_launch(void* const* d_in, const int* in_sizes, int n_in,
                              void* d_out, int out_size, void* d_ws, size_t ws_size,
                              hipStream_t stream) {
  const float* x_c = (const float*)d_in[0];
  const float* x_v = (const float*)d_in[1];
  const float* x_a = (const float*)d_in[2];
  const int* c2v_s = (const int*)d_in[3];
  const int* c2v_t = (const int*)d_in[4];
  const int* a2v_s = (const int*)d_in[5];
  const int* a2v_t = (const int*)d_in[6];
  const float* ea_c2v = (const float*)d_in[7];
  const float* ea_a2v = (const float*)d_in[8];
  const float* gv_W1 = (const float*)d_in[9];
  const float* gv_b1 = (const float*)d_in[10];
  const float* gv_W2 = (const float*)d_in[11];
  const float* gv_b2 = (const float*)d_in[12];
  const float* hv_W1 = (const float*)d_in[13];
  const float* hv_b1 = (const float*)d_in[14];
  const float* hv_W2 = (const float*)d_in[15];
  const float* hv_b2 = (const float*)d_in[16];
  const float* fv_W1 = (const float*)d_in[17];
  const float* fv_b1 = (const float*)d_in[18];
  const float* fv_W2 = (const float*)d_in[19];
  const float* fv_b2 = (const float*)d_in[20];
  const float* ga_W1 = (const float*)d_in[21];
  const float* ga_b1 = (const float*)d_in[22];
  const float* ga_W2 = (const float*)d_in[23];
  const float* ga_b2 = (const float*)d_in[24];
  const float* fa_W1 = (const float*)d_in[25];
  const float* fa_b1 = (const float*)d_in[26];
  const float* fa_W2 = (const float*)d_in[27];
  const float* fa_b2 = (const float*)d_in[28];

  // ---- workspace layout: ~35.7 MB (proven envelope ~39.9 MB) ----
  int* ip = (int*)d_ws;
  int* deg_g = ip;                  // 100000
  int* deg_h = deg_g + N_V;         // 100000
  int* deg_a = deg_h + N_V;         // 5000
  int* ctr = deg_a + N_A;           // 4
  float* hacc = (float*)(ctr + 4);              // N_V*32 (becomes fv in-place)
  float* hacc_a = hacc + (size_t)N_V * EMB;     // N_A*32
  int* off_g = (int*)(hacc_a + (size_t)N_A * EMB);  // 100000
  int* off_h = off_g + N_V;                         // 100000
  int* off_a = off_h + N_V;                         // 5000
  // Payload region P: 2.0M u64 (16 MB), byte offset 15,080,016 (8B-aligned).
  //   phase g: pay_g = P[0..1.6M)
  //   phase h/a: pay_h = P[0..1.0M), pay_a = P[1.0M..2.0M)
  u64* P = (u64*)(off_a + N_A);
  u64* pay_a = P + E_A2V;
  // rank arrays after P (u8 for g/h, u16 for a)
  u8* rank_g = (u8*)(P + 2 * E_A2V);       // 1.6M B
  u8* rank_h = rank_g + E_C2V;             // 1.0M B
  unsigned short* rank_a = (unsigned short*)(rank_h + E_A2V);  // 2.0M B

  hipMemsetAsync(d_ws, 0,
                 (size_t)205004 * sizeof(int) +
                     (size_t)(N_V + N_A) * EMB * sizeof(float),
                 stream);

  // g/h degrees + u8 ranks (fabric atomics: 2.6M)
  k_counts<<<NCH, 256, 0, stream>>>(c2v_t, a2v_t, deg_g, deg_h, rank_g, rank_h);
  // a-side degree + rank via LDS histogram (fabric atomics: ~0.3M)
  k_rank_a<<<(E_A2V + RBLK - 1) / RBLK, 256, 0, stream>>>(a2v_s, deg_a, rank_a);
  k_allocs<<<2 * NBV + NBA, 256, 0, stream>>>(deg_g, off_g, deg_h, off_h,
                                              deg_a, off_a, ctr);
  // g side: packed payload fill -> edge MLP + reduce -> hacc
  k_fill_g<<<8 * NCH, 256, 0, stream>>>(c2v_t, c2v_s, ea_c2v, off_g, rank_g, P);
  k_edge_v<0><<<E_C2V / 256, 256, 0, stream>>>(
      E_C2V, P, x_v, x_c,
      gv_W1, gv_b1, gv_W2, gv_b2, fv_W1 + (size_t)D_V * EMB, deg_g, hacc);
  // h + a payloads in one pass (P free after edge_g)
  k_fill_ha<<<8 * NCHA, 256, 0, stream>>>(a2v_t, a2v_s, ea_a2v,
                                          off_h, rank_h, P,
                                          off_a, rank_a, pay_a);
  k_edge_v<1><<<NCHA, 256, 0, stream>>>(
      E_A2V, P, x_v, x_a,
      hv_W1, hv_b1, hv_W2, hv_b2, fv_W1 + (size_t)(D_V + EMB) * EMB, deg_h,
      hacc);
  // f_v in-place: hacc rows become fv rows
  k_node_fv<<<(N_V + 255) / 256, 256, 0, stream>>>(
      x_v, hacc, fv_W1, fv_b1, fv_W2, fv_b2);
  // a side edge MLP + reduce -> hacc_a
  k_edge_a<<<NCHA, 256, 0, stream>>>(
      pay_a, x_a, hacc,
      ga_W1, ga_b1, ga_W2, ga_b2, fa_W1 + (size_t)D_A * EMB, deg_a, hacc_a);
  // f_a -> out
  k_node_fa<<<(N_A + 255) / 256, 256, 0, stream>>>(
      x_a, hacc_a, fa_W1, fa_b1, fa_W2, fa_b2, (float*)d_out);
}

// Round 19
// 608.524 us; speedup vs baseline: 1.4126x; 1.0084x over previous
//
#include <hip/hip_runtime.h>

// Problem constants (from reference)
#define N_C 50000
#define N_V 100000
#define N_A 5000
#define E_C2V 1600000
#define E_A2V 1000000
#define D_V 13
#define D_C 14
#define D_A 14
#define EMB 32

// Residue-major node-index permutation (XCD-local CSR lines; round 8).
#define PV(t) (((t) >> 3) + ((t)&7) * (N_V / 8))  // N_V/8 = 12500
#define PA(t) (((t) >> 3) + ((t)&7) * (N_A / 8))  // N_A/8 = 625
#define NCH (E_C2V / 256)                         // 6250 chunks, exact
#define NCHA ((E_A2V + 255) / 256)                // 3907
#define RBLK 16384                                // edges per rank_a block
#define NRA ((E_A2V + RBLK - 1) / RBLK)           // 62

typedef float v2f __attribute__((ext_vector_type(2)));
typedef float f32x4 __attribute__((ext_vector_type(4)));
typedef short bf16x8 __attribute__((ext_vector_type(8)));
typedef unsigned long long u64;
typedef unsigned char u8;

// Pack (key_hi:17b, key_lo:16b, ea as bf16 RNE) into one u64.
__device__ __forceinline__ u64 pack_edge(int hi, int lo, float ea) {
  unsigned b = __float_as_uint(ea);
  b += 0x7FFFu + ((b >> 16) & 1u);  // round-to-nearest-even to bf16
  return ((u64)(unsigned)hi << 32) | ((u64)(unsigned)(lo & 0xFFFF) << 16) |
         (u64)(b >> 16);
}

// bf16 RNE of one float (u16).
__device__ __forceinline__ unsigned short bf16r(float x) {
  unsigned u = __float_as_uint(x);
  u += 0x7FFFu + ((u >> 16) & 1u);
  return (unsigned short)(u >> 16);
}

// Pack two floats to bf16 pair (RNE) in one uint: low=a, high=b.
__device__ __forceinline__ unsigned bf16pk(float a, float b) {
  unsigned ua = __float_as_uint(a);
  ua += 0x7FFFu + ((ua >> 16) & 1u);
  unsigned ub = __float_as_uint(b);
  ub += 0x7FFFu + ((ub >> 16) & 1u);
  return (ua >> 16) | (ub & 0xFFFF0000u);
}

// h2[j] (16 x float2 = 32 channels) += v * Wrow[2j..2j+1] via v_pk_fma_f32.
__device__ __forceinline__ void accrow2(v2f* __restrict__ h, float v,
                                        const float* __restrict__ Wrow) {
  const v2f* w = (const v2f*)Wrow;
  v2f vv = {v, v};
#pragma unroll
  for (int j = 0; j < 16; ++j) h[j] = __builtin_elementwise_fma(vv, w[j], h[j]);
}

__device__ __forceinline__ void relu2(v2f* __restrict__ h) {
  v2f z = {0.0f, 0.0f};
#pragma unroll
  for (int j = 0; j < 16; ++j) h[j] = __builtin_elementwise_max(h[j], z);
}

__device__ __forceinline__ void layer2(v2f* __restrict__ o2,
                                       const v2f* __restrict__ h,
                                       const float* __restrict__ W2,
                                       const float* __restrict__ b2) {
  const v2f* b = (const v2f*)b2;
#pragma unroll
  for (int j = 0; j < 16; ++j) o2[j] = b[j];
#pragma unroll
  for (int k = 0; k < EMB; ++k) {
    float hk = h[k >> 1][k & 1];
    accrow2(o2, hk, W2 + k * EMB);
  }
}

// -------- MFMA layer2 (see r18): h (bf16, stride-18-u32 rows) -> outputs
// (bf16, [edge][ch], u16 stride 36), 8x mfma_f32_16x16x32_bf16.
__device__ __forceinline__ void layer2_mfma(
    unsigned short* __restrict__ vals_wv, int lane,
    const float* __restrict__ W2, const float* __restrict__ b2) {
  int q = lane >> 4;
  int n = lane & 15;
  bf16x8 bfr[2];
#pragma unroll
  for (int ni = 0; ni < 2; ++ni) {
#pragma unroll
    for (int j = 0; j < 8; ++j)
      bfr[ni][j] = (short)bf16r(W2[(q * 8 + j) * EMB + ni * 16 + n]);
  }
  union {
    u64 d[2];
    bf16x8 v;
  } afr[4];
#pragma unroll
  for (int mi = 0; mi < 4; ++mi) {
    const u64* rp =
        (const u64*)((const char*)vals_wv + (size_t)(mi * 16 + n) * 72 + q * 16);
    afr[mi].d[0] = rp[0];
    afr[mi].d[1] = rp[1];
  }
  float bb0 = b2[n], bb1 = b2[16 + n];
#pragma unroll
  for (int mi = 0; mi < 4; ++mi) {
#pragma unroll
    for (int ni = 0; ni < 2; ++ni) {
      f32x4 c = {0.f, 0.f, 0.f, 0.f};
      c = __builtin_amdgcn_mfma_f32_16x16x32_bf16(afr[mi].v, bfr[ni], c, 0, 0, 0);
      float bb = ni ? bb1 : bb0;
#pragma unroll
      for (int r = 0; r < 4; ++r) {
        float v = fmaxf(c[r] + bb, 0.0f);
        vals_wv[(size_t)(mi * 16 + q * 4 + r) * 36 + ni * 16 + n] = bf16r(v);
      }
    }
  }
}

// -------- MERGED: g/h degree+rank (fabric atomics) AND a-side LDS-histogram
// rank (block-range split; independent outputs run concurrently).
// rank_a trick: pass2 seeds hist[b] with the node's global base (atomicAdd
// return), pass3's LDS atomicAdd then returns base+local = global rank.
__global__ __launch_bounds__(256) void k_counts_all(
    const int* __restrict__ c2v_t, const int* __restrict__ a2v_t,
    const int* __restrict__ a2v_s,
    int* __restrict__ deg_g, int* __restrict__ deg_h, int* __restrict__ deg_a,
    u8* __restrict__ rank_g, u8* __restrict__ rank_h,
    unsigned short* __restrict__ rank_a) {
  __shared__ unsigned int hist[N_A];  // 20 KB (rank_a branch only)
  if (blockIdx.x < NCH) {
    int e = blockIdx.x * 256 + threadIdx.x;  // exact
    int t = c2v_t[e];
    rank_g[e] = (u8)atomicAdd(&deg_g[PV(t)], 1);
    if (e < E_A2V) {
      int th = a2v_t[e];
      rank_h[e] = (u8)atomicAdd(&deg_h[PV(th)], 1);
    }
  } else {
    int e0 = (int)(blockIdx.x - NCH) * RBLK;
    for (int b = threadIdx.x; b < N_A; b += 256) hist[b] = 0;
    __syncthreads();
    for (int i = threadIdx.x; i < RBLK; i += 256) {
      int e = e0 + i;
      if (e < E_A2V) atomicAdd(&hist[a2v_s[e]], 1u);
    }
    __syncthreads();
    for (int b = threadIdx.x; b < N_A; b += 256) {
      unsigned c = hist[b];
      hist[b] = c ? (unsigned)atomicAdd(&deg_a[PA(b)], (int)c) : 0u;
    }
    __syncthreads();
    for (int i = threadIdx.x; i < RBLK; i += 256) {
      int e = e0 + i;
      if (e < E_A2V)
        rank_a[e] = (unsigned short)atomicAdd(&hist[a2v_s[e]], 1u);
    }
  }
}

// -------- merged slot allocation (order-agnostic disjoint ranges)
#define NBV ((N_V + 255) / 256)  // 391
#define NBA ((N_A + 255) / 256)  // 20
__global__ __launch_bounds__(256) void k_allocs(
    const int* __restrict__ deg_g, int* __restrict__ off_g,
    const int* __restrict__ deg_h, int* __restrict__ off_h,
    const int* __restrict__ deg_a, int* __restrict__ off_a,
    int* __restrict__ ctr) {
  const int* deg;
  int* off;
  int* c;
  int i, n;
  if (blockIdx.x < NBV) {
    i = blockIdx.x * 256 + threadIdx.x;
    deg = deg_g; off = off_g; c = ctr + 0; n = N_V;
  } else if (blockIdx.x < 2 * NBV) {
    i = (blockIdx.x - NBV) * 256 + threadIdx.x;
    deg = deg_h; off = off_h; c = ctr + 1; n = N_V;
  } else {
    i = (blockIdx.x - 2 * NBV) * 256 + threadIdx.x;
    deg = deg_a; off = off_a; c = ctr + 2; n = N_A;
  }
  int lane = threadIdx.x & 63;
  int d = (i < n) ? deg[i] : 0;
  int v = d;
#pragma unroll
  for (int s = 1; s < 64; s <<= 1) {
    int t = __shfl_up(v, s, 64);
    if (lane >= s) v += t;
  }
  int total = __shfl(v, 63, 64);
  int base = 0;
  if (lane == 63) base = atomicAdd(c, total);
  base = __shfl(base, 63, 64);
  if (i < n) off[i] = base + v - d;
}

// -------- fill device helpers (atomic-free, one 8-B scattered store/edge)
__device__ __forceinline__ void fill_g_body(
    int b, int tid, const int* __restrict__ c2v_t,
    const int* __restrict__ c2v_s, const float* __restrict__ ea,
    const int* __restrict__ off_g, const u8* __restrict__ rank_g,
    u64* __restrict__ pay) {
  int res = b & 7;
  int e = (b >> 3) * 256 + tid;  // exact for g
  int t = c2v_t[e];
  if ((t & 7) == res) {
    int pos = off_g[PV(t)] + (int)rank_g[e];
    pay[pos] = pack_edge(t, c2v_s[e], ea[e]);  // s < 50000 < 2^16
  }
}

__device__ __forceinline__ void fill_ha_body(
    int b, int tid, const int* __restrict__ a2v_t,
    const int* __restrict__ a2v_s, const float* __restrict__ ea,
    const int* __restrict__ off_h, const u8* __restrict__ rank_h,
    u64* __restrict__ pay_h, const int* __restrict__ off_a,
    const unsigned short* __restrict__ rank_a, u64* __restrict__ pay_a) {
  int res = b & 7;
  int e = (b >> 3) * 256 + tid;
  if (e >= E_A2V) return;
  int t = a2v_t[e];
  int a = a2v_s[e];
  u64 pk = pack_edge(t, a, ea[e]);
  if ((t & 7) == res) pay_h[off_h[PV(t)] + (int)rank_h[e]] = pk;
  if ((a & 7) == res) pay_a[off_a[PA(a)] + (int)rank_a[e]] = pk;
}

// separate fills (small-ws fallback: pay regions time-multiplexed)
__global__ __launch_bounds__(256) void k_fill_g(
    const int* __restrict__ c2v_t, const int* __restrict__ c2v_s,
    const float* __restrict__ ea, const int* __restrict__ off_g,
    const u8* __restrict__ rank_g, u64* __restrict__ pay) {
  fill_g_body(blockIdx.x, threadIdx.x, c2v_t, c2v_s, ea, off_g, rank_g, pay);
}

__global__ __launch_bounds__(256) void k_fill_ha(
    const int* __restrict__ a2v_t, const int* __restrict__ a2v_s,
    const float* __restrict__ ea,
    const int* __restrict__ off_h, const u8* __restrict__ rank_h,
    u64* __restrict__ pay_h,
    const int* __restrict__ off_a, const unsigned short* __restrict__ rank_a,
    u64* __restrict__ pay_a) {
  fill_ha_body(blockIdx.x, threadIdx.x, a2v_t, a2v_s, ea, off_h, rank_h,
               pay_h, off_a, rank_a, pay_a);
}

// merged fill (big-ws path: all three payloads disjoint -> one dispatch,
// g and ha halves execute concurrently)
__global__ __launch_bounds__(256) void k_fill_all(
    const int* __restrict__ c2v_t, const int* __restrict__ c2v_s,
    const float* __restrict__ ea_g_in,
    const int* __restrict__ a2v_t, const int* __restrict__ a2v_s,
    const float* __restrict__ ea_ha,
    const int* __restrict__ off_g, const u8* __restrict__ rank_g,
    u64* __restrict__ pay_g,
    const int* __restrict__ off_h, const u8* __restrict__ rank_h,
    u64* __restrict__ pay_h,
    const int* __restrict__ off_a, const unsigned short* __restrict__ rank_a,
    u64* __restrict__ pay_a) {
  if (blockIdx.x < 8 * NCH) {
    fill_g_body(blockIdx.x, threadIdx.x, c2v_t, c2v_s, ea_g_in, off_g, rank_g,
                pay_g);
  } else {
    fill_ha_body(blockIdx.x - 8 * NCH, threadIdx.x, a2v_t, a2v_s, ea_ha,
                 off_h, rank_h, pay_h, off_a, rank_a, pay_a);
  }
}

// -------- edge-parallel v-side edge MLP: layer1 packed-fp32, layer2 MFMA,
// half-split LDS segmented reduce + projection -> hacc.
template <int ADDMODE>
__global__ __launch_bounds__(256) void k_edge_v(
    int E, const u64* __restrict__ pay,
    const float* __restrict__ x_t,   // variable-node feats (13)
    const float* __restrict__ x_s,   // source feats (14), rows 8B-aligned
    const float* __restrict__ W1, const float* __restrict__ b1,
    const float* __restrict__ W2, const float* __restrict__ b2,
    const float* __restrict__ Wp,    // fW1 + (13 or 45)*32 projection slice
    const int* __restrict__ deg,     // residue-major indexed
    float* __restrict__ hacc) {
  __shared__ __align__(16) unsigned short vals[4][64][36];
  __shared__ int nidl[4][64];
  __shared__ float segx[4][2][32];
  int wv = threadIdx.x >> 6;
  int lane = threadIdx.x & 63;
  int slot = blockIdx.x * 256 + threadIdx.x;
  if ((slot & ~63) >= E) return;  // wave-uniform exit (E % 64 == 0)

  u64 p = pay[slot];
  int t = (int)(p >> 32);
  int s = (int)((p >> 16) & 0xFFFFull);
  float eav = __uint_as_float((unsigned)(p & 0xFFFFull) << 16);
  const float* xt = x_t + (size_t)t * D_V;

  v2f h[16];
  const v2f* b1v = (const v2f*)b1;
#pragma unroll
  for (int j = 0; j < 16; ++j) h[j] = b1v[j];
#pragma unroll
  for (int i = 0; i < D_V; ++i) accrow2(h, xt[i], W1 + i * EMB);
  const float2* xs2 = (const float2*)(x_s + (size_t)s * D_C);
#pragma unroll
  for (int i = 0; i < 7; ++i) {
    float2 wv2 = xs2[i];
    accrow2(h, wv2.x, W1 + (D_V + 2 * i) * EMB);
    accrow2(h, wv2.y, W1 + (D_V + 2 * i + 1) * EMB);
  }
  accrow2(h, eav, W1 + 27 * EMB);
  relu2(h);
  {
    unsigned* hm = (unsigned*)&vals[wv][0][0];
#pragma unroll
    for (int j = 0; j < 16; ++j)
      hm[lane * 18 + j] = bf16pk(h[j].x, h[j].y);
  }
  nidl[wv][lane] = t;
  layer2_mfma(&vals[wv][0][0], lane, W2, b2);
  {
    int half = lane >> 5;
    int j = lane & 31;
    float acc = 0.0f;
    int r0 = 0;
    for (int r = 0; r < 32; ++r) {
      int row = half * 32 + r;
      acc += __uint_as_float((unsigned)vals[wv][row][j] << 16);
      int cur = nidl[wv][row];
      bool flush = (r == 31) || (nidl[wv][row + 1] != cur);
      if (flush) {
        float inv = 1.0f / fmaxf((float)deg[PV(cur)], 1.0f);
        segx[wv][half][j] = acc * inv;
        float out = 0.0f;
#pragma unroll
        for (int k = 0; k < EMB; ++k)
          out = fmaf(segx[wv][half][k], Wp[k * EMB + j], out);
        float* dst = &hacc[(size_t)cur * EMB + j];
        bool interior = (r0 > 0) && (r < 31);
        if (interior) {
          if (ADDMODE) out += *dst;
          *dst = out;
        } else {
          atomicAdd(dst, out);
        }
        acc = 0.0f;
        r0 = r + 1;
      }
    }
  }
}

// -------- edge-parallel a-side g_a MLP (FIN=47): layer1 packed, layer2 MFMA
__global__ __launch_bounds__(256) void k_edge_a(
    const u64* __restrict__ pay,
    const float* __restrict__ xa_g, const float* __restrict__ fv,
    const float* __restrict__ W1, const float* __restrict__ b1,
    const float* __restrict__ W2, const float* __restrict__ b2,
    const float* __restrict__ Wp,   // fa_W1 + 14*32
    const int* __restrict__ deg,
    float* __restrict__ hacc_a) {
  __shared__ __align__(16) unsigned short vals[4][64][36];
  __shared__ int nidl[4][64];
  __shared__ float segx[4][2][32];
  int wv = threadIdx.x >> 6;
  int lane = threadIdx.x & 63;
  int slot = blockIdx.x * 256 + threadIdx.x;
  if ((slot & ~63) >= E_A2V) return;

  u64 p = pay[slot];
  int t = (int)(p >> 32);
  int a = (int)((p >> 16) & 0xFFFFull);
  float eav = __uint_as_float((unsigned)(p & 0xFFFFull) << 16);

  v2f h[16];
  const v2f* b1v = (const v2f*)b1;
#pragma unroll
  for (int j = 0; j < 16; ++j) h[j] = b1v[j];
  const float2* ps2 = (const float2*)(xa_g + (size_t)a * D_A);
#pragma unroll
  for (int i = 0; i < 7; ++i) {
    float2 wv2 = ps2[i];
    accrow2(h, wv2.x, W1 + (2 * i) * EMB);
    accrow2(h, wv2.y, W1 + (2 * i + 1) * EMB);
  }
  const float4* pf = (const float4*)(fv + (size_t)t * EMB);
#pragma unroll
  for (int q = 0; q < 8; ++q) {
    float4 f = pf[q];
    accrow2(h, f.x, W1 + (D_A + 4 * q) * EMB);
    accrow2(h, f.y, W1 + (D_A + 4 * q + 1) * EMB);
    accrow2(h, f.z, W1 + (D_A + 4 * q + 2) * EMB);
    accrow2(h, f.w, W1 + (D_A + 4 * q + 3) * EMB);
  }
  accrow2(h, eav, W1 + 46 * EMB);
  relu2(h);
  {
    unsigned* hm = (unsigned*)&vals[wv][0][0];
#pragma unroll
    for (int j = 0; j < 16; ++j)
      hm[lane * 18 + j] = bf16pk(h[j].x, h[j].y);
  }
  nidl[wv][lane] = a;
  layer2_mfma(&vals[wv][0][0], lane, W2, b2);
  {
    int half = lane >> 5;
    int j = lane & 31;
    float acc = 0.0f;
    int r0 = 0;
    for (int r = 0; r < 32; ++r) {
      int row = half * 32 + r;
      acc += __uint_as_float((unsigned)vals[wv][row][j] << 16);
      int cur = nidl[wv][row];
      bool flush = (r == 31) || (nidl[wv][row + 1] != cur);
      if (flush) {
        float inv = 1.0f / fmaxf((float)deg[PA(cur)], 1.0f);
        segx[wv][half][j] = acc * inv;
        float out = 0.0f;
#pragma unroll
        for (int k = 0; k < EMB; ++k)
          out = fmaf(segx[wv][half][k], Wp[k * EMB + j], out);
        float* dst = &hacc_a[(size_t)cur * EMB + j];
        bool interior = (r0 > 0) && (r < 31);
        if (interior) {
          *dst = out;  // sole writer (zeroed buffer, single dispatch)
        } else {
          atomicAdd(dst, out);
        }
        acc = 0.0f;
        r0 = r + 1;
      }
    }
  }
}

// -------- f_v node MLP, IN-PLACE on hacc (same thread reads+writes row v).
__global__ __launch_bounds__(256) void k_node_fv(
    const float* __restrict__ xv_g, float* hf,
    const float* __restrict__ fW1, const float* __restrict__ fb1,
    const float* __restrict__ fW2, const float* __restrict__ fb2) {
  int v = blockIdx.x * blockDim.x + threadIdx.x;
  if (v >= N_V) return;
  v2f* row = (v2f*)(hf + (size_t)v * EMB);
  const v2f* bv = (const v2f*)fb1;
  v2f h[16];
#pragma unroll
  for (int j = 0; j < 16; ++j) h[j] = bv[j] + row[j];
  const float* pv = xv_g + (size_t)v * D_V;
#pragma unroll
  for (int i = 0; i < D_V; ++i) accrow2(h, pv[i], fW1 + i * EMB);
  relu2(h);
  v2f o2[16];
  layer2(o2, h, fW2, fb2);
  v2f z = {0.0f, 0.0f};
#pragma unroll
  for (int j = 0; j < 16; ++j)
    row[j] = __builtin_elementwise_max(o2[j], z);  // relu_out (+idempotent)
}

// -------- f_a node MLP on pre-accumulated hidden -> d_out (packed)
__global__ __launch_bounds__(256) void k_node_fa(
    const float* __restrict__ xa, const float* __restrict__ hacc_a,
    const float* __restrict__ W1, const float* __restrict__ b1,
    const float* __restrict__ W2, const float* __restrict__ b2,
    float* __restrict__ out) {
  int a = blockIdx.x * blockDim.x + threadIdx.x;
  if (a >= N_A) return;
  const v2f* hr = (const v2f*)(hacc_a + (size_t)a * EMB);
  const v2f* bv = (const v2f*)b1;
  v2f h[16];
#pragma unroll
  for (int j = 0; j < 16; ++j) h[j] = bv[j] + hr[j];
  const float2* pa = (const float2*)(xa + (size_t)a * D_A);
#pragma unroll
  for (int i = 0; i < 7; ++i) {
    float2 w = pa[i];
    accrow2(h, w.x, W1 + (2 * i) * EMB);
    accrow2(h, w.y, W1 + (2 * i + 1) * EMB);
  }
  relu2(h);
  v2f o2[16];
  layer2(o2, h, W2, b2);
  v2f z = {0.0f, 0.0f};
  v2f* dst = (v2f*)(out + (size_t)a * EMB);
#pragma unroll
  for (int j = 0; j < 16; ++j)
    dst[j] = __builtin_elementwise_max(o2[j], z);
}

extern "C" void kernel_launch(void* const* d_in, const int* in_sizes, int n_in,
                              void* d_out, int out_size, void* d_ws, size_t ws_size,
                              hipStream_t stream) {
  const float* x_c = (const float*)d_in[0];
  const float* x_v = (const float*)d_in[1];
  const float* x_a = (const float*)d_in[2];
  const int* c2v_s = (const int*)d_in[3];
  const int* c2v_t = (const int*)d_in[4];
  const int* a2v_s = (const int*)d_in[5];
  const int* a2v_t = (const int*)d_in[6];
  const float* ea_c2v = (const float*)d_in[7];
  const float* ea_a2v = (const float*)d_in[8];
  const float* gv_W1 = (const float*)d_in[9];
  const float* gv_b1 = (const float*)d_in[10];
  const float* gv_W2 = (const float*)d_in[11];
  const float* gv_b2 = (const float*)d_in[12];
  const float* hv_W1 = (const float*)d_in[13];
  const float* hv_b1 = (const float*)d_in[14];
  const float* hv_W2 = (const float*)d_in[15];
  const float* hv_b2 = (const float*)d_in[16];
  const float* fv_W1 = (const float*)d_in[17];
  const float* fv_b1 = (const float*)d_in[18];
  const float* fv_W2 = (const float*)d_in[19];
  const float* fv_b2 = (const float*)d_in[20];
  const float* ga_W1 = (const float*)d_in[21];
  const float* ga_b1 = (const float*)d_in[22];
  const float* ga_W2 = (const float*)d_in[23];
  const float* ga_b2 = (const float*)d_in[24];
  const float* fa_W1 = (const float*)d_in[25];
  const float* fa_b1 = (const float*)d_in[26];
  const float* fa_W2 = (const float*)d_in[27];
  const float* fa_b2 = (const float*)d_in[28];

  // ---- workspace layout ----
  // Fixed prefix: deg/ctr (205,004 ints, memset) + hacc/hacc_a (memset) +
  // off arrays -> 3,770,004 ints = 15,080,016 B (8B-aligned).
  int* ip = (int*)d_ws;
  int* deg_g = ip;                  // 100000
  int* deg_h = deg_g + N_V;         // 100000
  int* deg_a = deg_h + N_V;         // 5000
  int* ctr = deg_a + N_A;           // 4
  float* hacc = (float*)(ctr + 4);              // N_V*32 (becomes fv in-place)
  float* hacc_a = hacc + (size_t)N_V * EMB;     // N_A*32
  int* off_g = (int*)(hacc_a + (size_t)N_A * EMB);  // 100000
  int* off_h = off_g + N_V;                         // 100000
  int* off_a = off_h + N_V;                         // 5000
  u64* P = (u64*)(off_a + N_A);

  // Big path (ws >= 48.5 MB): payloads fully disjoint -> merged single-pass
  // fill. Small path (r18-proven 35.7 MB): pay regions time-multiplexed.
  const size_t base_bytes = (size_t)3770004 * 4;
  const size_t rank_bytes = (size_t)E_C2V + E_A2V + 2 * E_A2V;  // u8,u8,u16
  const size_t need_big = base_bytes + (size_t)3600000 * 8 + rank_bytes;
  bool big = ws_size >= need_big;

  u64* pay_g = P;
  u64* pay_h = big ? (P + E_C2V) : P;
  u64* pay_a = big ? (P + E_C2V + E_A2V) : (P + E_A2V);
  size_t p_total = big ? 3600000 : 2000000;
  u8* rank_g = (u8*)(P + p_total);
  u8* rank_h = rank_g + E_C2V;
  unsigned short* rank_a = (unsigned short*)(rank_h + E_A2V);

  hipMemsetAsync(d_ws, 0,
                 (size_t)205004 * sizeof(int) +
                     (size_t)(N_V + N_A) * EMB * sizeof(float),
                 stream);

  // merged: g/h degree+rank atomics || a-side LDS-histogram rank
  k_counts_all<<<NCH + NRA, 256, 0, stream>>>(
      c2v_t, a2v_t, a2v_s, deg_g, deg_h, deg_a, rank_g, rank_h, rank_a);
  k_allocs<<<2 * NBV + NBA, 256, 0, stream>>>(deg_g, off_g, deg_h, off_h,
                                              deg_a, off_a, ctr);
  if (big) {
    // one fill dispatch: g and ha halves run concurrently
    k_fill_all<<<8 * NCH + 8 * NCHA, 256, 0, stream>>>(
        c2v_t, c2v_s, ea_c2v, a2v_t, a2v_s, ea_a2v,
        off_g, rank_g, pay_g, off_h, rank_h, pay_h, off_a, rank_a, pay_a);
    k_edge_v<0><<<E_C2V / 256, 256, 0, stream>>>(
        E_C2V, pay_g, x_v, x_c, gv_W1, gv_b1, gv_W2, gv_b2,
        fv_W1 + (size_t)D_V * EMB, deg_g, hacc);
  } else {
    k_fill_g<<<8 * NCH, 256, 0, stream>>>(c2v_t, c2v_s, ea_c2v, off_g, rank_g,
                                          pay_g);
    k_edge_v<0><<<E_C2V / 256, 256, 0, stream>>>(
        E_C2V, pay_g, x_v, x_c, gv_W1, gv_b1, gv_W2, gv_b2,
        fv_W1 + (size_t)D_V * EMB, deg_g, hacc);
    k_fill_ha<<<8 * NCHA, 256, 0, stream>>>(a2v_t, a2v_s, ea_a2v,
                                            off_h, rank_h, pay_h,
                                            off_a, rank_a, pay_a);
  }
  k_edge_v<1><<<NCHA, 256, 0, stream>>>(
      E_A2V, pay_h, x_v, x_a, hv_W1, hv_b1, hv_W2, hv_b2,
      fv_W1 + (size_t)(D_V + EMB) * EMB, deg_h, hacc);
  // f_v in-place: hacc rows become fv rows
  k_node_fv<<<(N_V + 255) / 256, 256, 0, stream>>>(
      x_v, hacc, fv_W1, fv_b1, fv_W2, fv_b2);
  // a side edge MLP + reduce -> hacc_a
  k_edge_a<<<NCHA, 256, 0, stream>>>(
      pay_a, x_a, hacc, ga_W1, ga_b1, ga_W2, ga_b2,
      fa_W1 + (size_t)D_A * EMB, deg_a, hacc_a);
  // f_a -> out
  k_node_fa<<<(N_A + 255) / 256, 256, 0, stream>>>(
      x_a, hacc_a, fa_W1, fa_b1, fa_W2, fa_b2, (float*)d_out);
}

// Round 20
// 598.286 us; speedup vs baseline: 1.4368x; 1.0171x over previous
//
#include <hip/hip_runtime.h>

// Problem constants (from reference)
#define N_C 50000
#define N_V 100000
#define N_A 5000
#define E_C2V 1600000
#define E_A2V 1000000
#define D_V 13
#define D_C 14
#define D_A 14
#define EMB 32

// Residue-major node-index permutation (XCD-local CSR lines; round 8).
#define PV(t) (((t) >> 3) + ((t)&7) * (N_V / 8))  // N_V/8 = 12500
#define PA(t) (((t) >> 3) + ((t)&7) * (N_A / 8))  // N_A/8 = 625
#define NCH (E_C2V / 256)                         // 6250 chunks, exact
#define NCHA ((E_A2V + 255) / 256)                // 3907
#define RBLK 16384                                // edges per rank_a block
#define NRA ((E_A2V + RBLK - 1) / RBLK)           // 62

typedef float v2f __attribute__((ext_vector_type(2)));
typedef float f32x4 __attribute__((ext_vector_type(4)));
typedef short bf16x8 __attribute__((ext_vector_type(8)));
typedef unsigned long long u64;
typedef unsigned char u8;

// Pack (key_hi:17b, key_lo:16b, ea as bf16 RNE) into one u64.
__device__ __forceinline__ u64 pack_edge(int hi, int lo, float ea) {
  unsigned b = __float_as_uint(ea);
  b += 0x7FFFu + ((b >> 16) & 1u);  // round-to-nearest-even to bf16
  return ((u64)(unsigned)hi << 32) | ((u64)(unsigned)(lo & 0xFFFF) << 16) |
         (u64)(b >> 16);
}

// bf16 RNE of one float (u16).
__device__ __forceinline__ unsigned short bf16r(float x) {
  unsigned u = __float_as_uint(x);
  u += 0x7FFFu + ((u >> 16) & 1u);
  return (unsigned short)(u >> 16);
}

// Pack two floats to bf16 pair (RNE) in one uint: low=a, high=b.
__device__ __forceinline__ unsigned bf16pk(float a, float b) {
  unsigned ua = __float_as_uint(a);
  ua += 0x7FFFu + ((ua >> 16) & 1u);
  unsigned ub = __float_as_uint(b);
  ub += 0x7FFFu + ((ub >> 16) & 1u);
  return (ua >> 16) | (ub & 0xFFFF0000u);
}

// h2[j] (16 x float2 = 32 channels) += v * Wrow[2j..2j+1] via v_pk_fma_f32.
__device__ __forceinline__ void accrow2(v2f* __restrict__ h, float v,
                                        const float* __restrict__ Wrow) {
  const v2f* w = (const v2f*)Wrow;
  v2f vv = {v, v};
#pragma unroll
  for (int j = 0; j < 16; ++j) h[j] = __builtin_elementwise_fma(vv, w[j], h[j]);
}

__device__ __forceinline__ void relu2(v2f* __restrict__ h) {
  v2f z = {0.0f, 0.0f};
#pragma unroll
  for (int j = 0; j < 16; ++j) h[j] = __builtin_elementwise_max(h[j], z);
}

__device__ __forceinline__ void layer2(v2f* __restrict__ o2,
                                       const v2f* __restrict__ h,
                                       const float* __restrict__ W2,
                                       const float* __restrict__ b2) {
  const v2f* b = (const v2f*)b2;
#pragma unroll
  for (int j = 0; j < 16; ++j) o2[j] = b[j];
#pragma unroll
  for (int k = 0; k < EMB; ++k) {
    float hk = h[k >> 1][k & 1];
    accrow2(o2, hk, W2 + k * EMB);
  }
}

// -------- MFMA layer2 (see r18): h (bf16, stride-18-u32 rows) -> outputs
// (bf16, [edge][ch], u16 stride 36), 8x mfma_f32_16x16x32_bf16.
__device__ __forceinline__ void layer2_mfma(
    unsigned short* __restrict__ vals_wv, int lane,
    const float* __restrict__ W2, const float* __restrict__ b2) {
  int q = lane >> 4;
  int n = lane & 15;
  bf16x8 bfr[2];
#pragma unroll
  for (int ni = 0; ni < 2; ++ni) {
#pragma unroll
    for (int j = 0; j < 8; ++j)
      bfr[ni][j] = (short)bf16r(W2[(q * 8 + j) * EMB + ni * 16 + n]);
  }
  union {
    u64 d[2];
    bf16x8 v;
  } afr[4];
#pragma unroll
  for (int mi = 0; mi < 4; ++mi) {
    const u64* rp =
        (const u64*)((const char*)vals_wv + (size_t)(mi * 16 + n) * 72 + q * 16);
    afr[mi].d[0] = rp[0];
    afr[mi].d[1] = rp[1];
  }
  float bb0 = b2[n], bb1 = b2[16 + n];
#pragma unroll
  for (int mi = 0; mi < 4; ++mi) {
#pragma unroll
    for (int ni = 0; ni < 2; ++ni) {
      f32x4 c = {0.f, 0.f, 0.f, 0.f};
      c = __builtin_amdgcn_mfma_f32_16x16x32_bf16(afr[mi].v, bfr[ni], c, 0, 0, 0);
      float bb = ni ? bb1 : bb0;
#pragma unroll
      for (int r = 0; r < 4; ++r) {
        float v = fmaxf(c[r] + bb, 0.0f);
        vals_wv[(size_t)(mi * 16 + q * 4 + r) * 36 + ni * 16 + n] = bf16r(v);
      }
    }
  }
}

// -------- MERGED counts: a-side LDS-histogram blocks FIRST (long-running,
// must start at t=0 to hide under the g/h atomic stream — r19 had them last
// and they added ~45 us of pure tail), then g/h degree+rank blocks.
__global__ __launch_bounds__(256) void k_counts_all(
    const int* __restrict__ c2v_t, const int* __restrict__ a2v_t,
    const int* __restrict__ a2v_s,
    int* __restrict__ deg_g, int* __restrict__ deg_h, int* __restrict__ deg_a,
    u8* __restrict__ rank_g, u8* __restrict__ rank_h,
    unsigned short* __restrict__ rank_a) {
  __shared__ unsigned int hist[N_A];  // 20 KB; 8 blocks/CU still = 32 waves
  if (blockIdx.x < NRA) {
    int e0 = (int)blockIdx.x * RBLK;
    for (int b = threadIdx.x; b < N_A; b += 256) hist[b] = 0;
    __syncthreads();
    for (int i = threadIdx.x; i < RBLK; i += 256) {
      int e = e0 + i;
      if (e < E_A2V) atomicAdd(&hist[a2v_s[e]], 1u);
    }
    __syncthreads();
    for (int b = threadIdx.x; b < N_A; b += 256) {
      unsigned c = hist[b];
      hist[b] = c ? (unsigned)atomicAdd(&deg_a[PA(b)], (int)c) : 0u;
    }
    __syncthreads();
    for (int i = threadIdx.x; i < RBLK; i += 256) {
      int e = e0 + i;
      if (e < E_A2V)
        rank_a[e] = (unsigned short)atomicAdd(&hist[a2v_s[e]], 1u);
    }
  } else {
    int e = (int)(blockIdx.x - NRA) * 256 + threadIdx.x;  // exact range
    int t = c2v_t[e];
    rank_g[e] = (u8)atomicAdd(&deg_g[PV(t)], 1);
    if (e < E_A2V) {
      int th = a2v_t[e];
      rank_h[e] = (u8)atomicAdd(&deg_h[PV(th)], 1);
    }
  }
}

// -------- merged slot allocation (order-agnostic disjoint ranges)
#define NBV ((N_V + 255) / 256)  // 391
#define NBA ((N_A + 255) / 256)  // 20
__global__ __launch_bounds__(256) void k_allocs(
    const int* __restrict__ deg_g, int* __restrict__ off_g,
    const int* __restrict__ deg_h, int* __restrict__ off_h,
    const int* __restrict__ deg_a, int* __restrict__ off_a,
    int* __restrict__ ctr) {
  const int* deg;
  int* off;
  int* c;
  int i, n;
  if (blockIdx.x < NBV) {
    i = blockIdx.x * 256 + threadIdx.x;
    deg = deg_g; off = off_g; c = ctr + 0; n = N_V;
  } else if (blockIdx.x < 2 * NBV) {
    i = (blockIdx.x - NBV) * 256 + threadIdx.x;
    deg = deg_h; off = off_h; c = ctr + 1; n = N_V;
  } else {
    i = (blockIdx.x - 2 * NBV) * 256 + threadIdx.x;
    deg = deg_a; off = off_a; c = ctr + 2; n = N_A;
  }
  int lane = threadIdx.x & 63;
  int d = (i < n) ? deg[i] : 0;
  int v = d;
#pragma unroll
  for (int s = 1; s < 64; s <<= 1) {
    int t = __shfl_up(v, s, 64);
    if (lane >= s) v += t;
  }
  int total = __shfl(v, 63, 64);
  int base = 0;
  if (lane == 63) base = atomicAdd(c, total);
  base = __shfl(base, 63, 64);
  if (i < n) off[i] = base + v - d;
}

// -------- fill device helpers (atomic-free, one 8-B scattered store/edge)
__device__ __forceinline__ void fill_g_body(
    int b, int tid, const int* __restrict__ c2v_t,
    const int* __restrict__ c2v_s, const float* __restrict__ ea,
    const int* __restrict__ off_g, const u8* __restrict__ rank_g,
    u64* __restrict__ pay) {
  int res = b & 7;
  int e = (b >> 3) * 256 + tid;  // exact for g
  int t = c2v_t[e];
  if ((t & 7) == res) {
    int pos = off_g[PV(t)] + (int)rank_g[e];
    pay[pos] = pack_edge(t, c2v_s[e], ea[e]);  // s < 50000 < 2^16
  }
}

__device__ __forceinline__ void fill_ha_body(
    int b, int tid, const int* __restrict__ a2v_t,
    const int* __restrict__ a2v_s, const float* __restrict__ ea,
    const int* __restrict__ off_h, const u8* __restrict__ rank_h,
    u64* __restrict__ pay_h, const int* __restrict__ off_a,
    const unsigned short* __restrict__ rank_a, u64* __restrict__ pay_a) {
  int res = b & 7;
  int e = (b >> 3) * 256 + tid;
  if (e >= E_A2V) return;
  int t = a2v_t[e];
  int a = a2v_s[e];
  u64 pk = pack_edge(t, a, ea[e]);
  if ((t & 7) == res) pay_h[off_h[PV(t)] + (int)rank_h[e]] = pk;
  if ((a & 7) == res) pay_a[off_a[PA(a)] + (int)rank_a[e]] = pk;
}

// separate fills (small-ws fallback: pay regions time-multiplexed)
__global__ __launch_bounds__(256) void k_fill_g(
    const int* __restrict__ c2v_t, const int* __restrict__ c2v_s,
    const float* __restrict__ ea, const int* __restrict__ off_g,
    const u8* __restrict__ rank_g, u64* __restrict__ pay) {
  fill_g_body(blockIdx.x, threadIdx.x, c2v_t, c2v_s, ea, off_g, rank_g, pay);
}

__global__ __launch_bounds__(256) void k_fill_ha(
    const int* __restrict__ a2v_t, const int* __restrict__ a2v_s,
    const float* __restrict__ ea,
    const int* __restrict__ off_h, const u8* __restrict__ rank_h,
    u64* __restrict__ pay_h,
    const int* __restrict__ off_a, const unsigned short* __restrict__ rank_a,
    u64* __restrict__ pay_a) {
  fill_ha_body(blockIdx.x, threadIdx.x, a2v_t, a2v_s, ea, off_h, rank_h,
               pay_h, off_a, rank_a, pay_a);
}

// merged fill (big-ws path: all three payloads disjoint -> one dispatch)
__global__ __launch_bounds__(256) void k_fill_all(
    const int* __restrict__ c2v_t, const int* __restrict__ c2v_s,
    const float* __restrict__ ea_g_in,
    const int* __restrict__ a2v_t, const int* __restrict__ a2v_s,
    const float* __restrict__ ea_ha,
    const int* __restrict__ off_g, const u8* __restrict__ rank_g,
    u64* __restrict__ pay_g,
    const int* __restrict__ off_h, const u8* __restrict__ rank_h,
    u64* __restrict__ pay_h,
    const int* __restrict__ off_a, const unsigned short* __restrict__ rank_a,
    u64* __restrict__ pay_a) {
  if (blockIdx.x < 8 * NCH) {
    fill_g_body(blockIdx.x, threadIdx.x, c2v_t, c2v_s, ea_g_in, off_g, rank_g,
                pay_g);
  } else {
    fill_ha_body(blockIdx.x - 8 * NCH, threadIdx.x, a2v_t, a2v_s, ea_ha,
                 off_h, rank_h, pay_h, off_a, rank_a, pay_a);
  }
}

// -------- edge-parallel v-side edge MLP: layer1 packed-fp32, layer2 MFMA,
// half-split LDS segmented reduce + projection -> hacc.
template <int ADDMODE>
__global__ __launch_bounds__(256) void k_edge_v(
    int E, const u64* __restrict__ pay,
    const float* __restrict__ x_t,   // variable-node feats (13)
    const float* __restrict__ x_s,   // source feats (14), rows 8B-aligned
    const float* __restrict__ W1, const float* __restrict__ b1,
    const float* __restrict__ W2, const float* __restrict__ b2,
    const float* __restrict__ Wp,    // fW1 + (13 or 45)*32 projection slice
    const int* __restrict__ deg,     // residue-major indexed
    float* __restrict__ hacc) {
  __shared__ __align__(16) unsigned short vals[4][64][36];
  __shared__ int nidl[4][64];
  __shared__ float segx[4][2][32];
  int wv = threadIdx.x >> 6;
  int lane = threadIdx.x & 63;
  int slot = blockIdx.x * 256 + threadIdx.x;
  if ((slot & ~63) >= E) return;  // wave-uniform exit (E % 64 == 0)

  u64 p = pay[slot];
  int t = (int)(p >> 32);
  int s = (int)((p >> 16) & 0xFFFFull);
  float eav = __uint_as_float((unsigned)(p & 0xFFFFull) << 16);
  const float* xt = x_t + (size_t)t * D_V;

  v2f h[16];
  const v2f* b1v = (const v2f*)b1;
#pragma unroll
  for (int j = 0; j < 16; ++j) h[j] = b1v[j];
#pragma unroll
  for (int i = 0; i < D_V; ++i) accrow2(h, xt[i], W1 + i * EMB);
  const float2* xs2 = (const float2*)(x_s + (size_t)s * D_C);
#pragma unroll
  for (int i = 0; i < 7; ++i) {
    float2 wv2 = xs2[i];
    accrow2(h, wv2.x, W1 + (D_V + 2 * i) * EMB);
    accrow2(h, wv2.y, W1 + (D_V + 2 * i + 1) * EMB);
  }
  accrow2(h, eav, W1 + 27 * EMB);
  relu2(h);
  {
    unsigned* hm = (unsigned*)&vals[wv][0][0];
#pragma unroll
    for (int j = 0; j < 16; ++j)
      hm[lane * 18 + j] = bf16pk(h[j].x, h[j].y);
  }
  nidl[wv][lane] = t;
  layer2_mfma(&vals[wv][0][0], lane, W2, b2);
  {
    int half = lane >> 5;
    int j = lane & 31;
    float acc = 0.0f;
    int r0 = 0;
    for (int r = 0; r < 32; ++r) {
      int row = half * 32 + r;
      acc += __uint_as_float((unsigned)vals[wv][row][j] << 16);
      int cur = nidl[wv][row];
      bool flush = (r == 31) || (nidl[wv][row + 1] != cur);
      if (flush) {
        float inv = 1.0f / fmaxf((float)deg[PV(cur)], 1.0f);
        segx[wv][half][j] = acc * inv;
        float out = 0.0f;
#pragma unroll
        for (int k = 0; k < EMB; ++k)
          out = fmaf(segx[wv][half][k], Wp[k * EMB + j], out);
        float* dst = &hacc[(size_t)cur * EMB + j];
        bool interior = (r0 > 0) && (r < 31);
        if (interior) {
          if (ADDMODE) out += *dst;
          *dst = out;
        } else {
          atomicAdd(dst, out);
        }
        acc = 0.0f;
        r0 = r + 1;
      }
    }
  }
}

// -------- edge-parallel a-side g_a MLP (FIN=47): layer1 packed, layer2 MFMA
__global__ __launch_bounds__(256) void k_edge_a(
    const u64* __restrict__ pay,
    const float* __restrict__ xa_g, const float* __restrict__ fv,
    const float* __restrict__ W1, const float* __restrict__ b1,
    const float* __restrict__ W2, const float* __restrict__ b2,
    const float* __restrict__ Wp,   // fa_W1 + 14*32
    const int* __restrict__ deg,
    float* __restrict__ hacc_a) {
  __shared__ __align__(16) unsigned short vals[4][64][36];
  __shared__ int nidl[4][64];
  __shared__ float segx[4][2][32];
  int wv = threadIdx.x >> 6;
  int lane = threadIdx.x & 63;
  int slot = blockIdx.x * 256 + threadIdx.x;
  if ((slot & ~63) >= E_A2V) return;

  u64 p = pay[slot];
  int t = (int)(p >> 32);
  int a = (int)((p >> 16) & 0xFFFFull);
  float eav = __uint_as_float((unsigned)(p & 0xFFFFull) << 16);

  v2f h[16];
  const v2f* b1v = (const v2f*)b1;
#pragma unroll
  for (int j = 0; j < 16; ++j) h[j] = b1v[j];
  const float2* ps2 = (const float2*)(xa_g + (size_t)a * D_A);
#pragma unroll
  for (int i = 0; i < 7; ++i) {
    float2 wv2 = ps2[i];
    accrow2(h, wv2.x, W1 + (2 * i) * EMB);
    accrow2(h, wv2.y, W1 + (2 * i + 1) * EMB);
  }
  const float4* pf = (const float4*)(fv + (size_t)t * EMB);
#pragma unroll
  for (int q = 0; q < 8; ++q) {
    float4 f = pf[q];
    accrow2(h, f.x, W1 + (D_A + 4 * q) * EMB);
    accrow2(h, f.y, W1 + (D_A + 4 * q + 1) * EMB);
    accrow2(h, f.z, W1 + (D_A + 4 * q + 2) * EMB);
    accrow2(h, f.w, W1 + (D_A + 4 * q + 3) * EMB);
  }
  accrow2(h, eav, W1 + 46 * EMB);
  relu2(h);
  {
    unsigned* hm = (unsigned*)&vals[wv][0][0];
#pragma unroll
    for (int j = 0; j < 16; ++j)
      hm[lane * 18 + j] = bf16pk(h[j].x, h[j].y);
  }
  nidl[wv][lane] = a;
  layer2_mfma(&vals[wv][0][0], lane, W2, b2);
  {
    int half = lane >> 5;
    int j = lane & 31;
    float acc = 0.0f;
    int r0 = 0;
    for (int r = 0; r < 32; ++r) {
      int row = half * 32 + r;
      acc += __uint_as_float((unsigned)vals[wv][row][j] << 16);
      int cur = nidl[wv][row];
      bool flush = (r == 31) || (nidl[wv][row + 1] != cur);
      if (flush) {
        float inv = 1.0f / fmaxf((float)deg[PA(cur)], 1.0f);
        segx[wv][half][j] = acc * inv;
        float out = 0.0f;
#pragma unroll
        for (int k = 0; k < EMB; ++k)
          out = fmaf(segx[wv][half][k], Wp[k * EMB + j], out);
        float* dst = &hacc_a[(size_t)cur * EMB + j];
        bool interior = (r0 > 0) && (r < 31);
        if (interior) {
          *dst = out;  // sole writer (zeroed buffer, single dispatch)
        } else {
          atomicAdd(dst, out);
        }
        acc = 0.0f;
        r0 = r + 1;
      }
    }
  }
}

// -------- f_v node MLP, IN-PLACE on hacc (same thread reads+writes row v).
__global__ __launch_bounds__(256) void k_node_fv(
    const float* __restrict__ xv_g, float* hf,
    const float* __restrict__ fW1, const float* __restrict__ fb1,
    const float* __restrict__ fW2, const float* __restrict__ fb2) {
  int v = blockIdx.x * blockDim.x + threadIdx.x;
  if (v >= N_V) return;
  v2f* row = (v2f*)(hf + (size_t)v * EMB);
  const v2f* bv = (const v2f*)fb1;
  v2f h[16];
#pragma unroll
  for (int j = 0; j < 16; ++j) h[j] = bv[j] + row[j];
  const float* pv = xv_g + (size_t)v * D_V;
#pragma unroll
  for (int i = 0; i < D_V; ++i) accrow2(h, pv[i], fW1 + i * EMB);
  relu2(h);
  v2f o2[16];
  layer2(o2, h, fW2, fb2);
  v2f z = {0.0f, 0.0f};
#pragma unroll
  for (int j = 0; j < 16; ++j)
    row[j] = __builtin_elementwise_max(o2[j], z);  // relu_out (+idempotent)
}

// -------- f_a node MLP on pre-accumulated hidden -> d_out (packed)
__global__ __launch_bounds__(256) void k_node_fa(
    const float* __restrict__ xa, const float* __restrict__ hacc_a,
    const float* __restrict__ W1, const float* __restrict__ b1,
    const float* __restrict__ W2, const float* __restrict__ b2,
    float* __restrict__ out) {
  int a = blockIdx.x * blockDim.x + threadIdx.x;
  if (a >= N_A) return;
  const v2f* hr = (const v2f*)(hacc_a + (size_t)a * EMB);
  const v2f* bv = (const v2f*)b1;
  v2f h[16];
#pragma unroll
  for (int j = 0; j < 16; ++j) h[j] = bv[j] + hr[j];
  const float2* pa = (const float2*)(xa + (size_t)a * D_A);
#pragma unroll
  for (int i = 0; i < 7; ++i) {
    float2 w = pa[i];
    accrow2(h, w.x, W1 + (2 * i) * EMB);
    accrow2(h, w.y, W1 + (2 * i + 1) * EMB);
  }
  relu2(h);
  v2f o2[16];
  layer2(o2, h, W2, b2);
  v2f z = {0.0f, 0.0f};
  v2f* dst = (v2f*)(out + (size_t)a * EMB);
#pragma unroll
  for (int j = 0; j < 16; ++j)
    dst[j] = __builtin_elementwise_max(o2[j], z);
}

extern "C" void kernel_launch(void* const* d_in, const int* in_sizes, int n_in,
                              void* d_out, int out_size, void* d_ws, size_t ws_size,
                              hipStream_t stream) {
  const float* x_c = (const float*)d_in[0];
  const float* x_v = (const float*)d_in[1];
  const float* x_a = (const float*)d_in[2];
  const int* c2v_s = (const int*)d_in[3];
  const int* c2v_t = (const int*)d_in[4];
  const int* a2v_s = (const int*)d_in[5];
  const int* a2v_t = (const int*)d_in[6];
  const float* ea_c2v = (const float*)d_in[7];
  const float* ea_a2v = (const float*)d_in[8];
  const float* gv_W1 = (const float*)d_in[9];
  const float* gv_b1 = (const float*)d_in[10];
  const float* gv_W2 = (const float*)d_in[11];
  const float* gv_b2 = (const float*)d_in[12];
  const float* hv_W1 = (const float*)d_in[13];
  const float* hv_b1 = (const float*)d_in[14];
  const float* hv_W2 = (const float*)d_in[15];
  const float* hv_b2 = (const float*)d_in[16];
  const float* fv_W1 = (const float*)d_in[17];
  const float* fv_b1 = (const float*)d_in[18];
  const float* fv_W2 = (const float*)d_in[19];
  const float* fv_b2 = (const float*)d_in[20];
  const float* ga_W1 = (const float*)d_in[21];
  const float* ga_b1 = (const float*)d_in[22];
  const float* ga_W2 = (const float*)d_in[23];
  const float* ga_b2 = (const float*)d_in[24];
  const float* fa_W1 = (const float*)d_in[25];
  const float* fa_b1 = (const float*)d_in[26];
  const float* fa_W2 = (const float*)d_in[27];
  const float* fa_b2 = (const float*)d_in[28];

  // ---- workspace layout (same as r19) ----
  int* ip = (int*)d_ws;
  int* deg_g = ip;                  // 100000
  int* deg_h = deg_g + N_V;         // 100000
  int* deg_a = deg_h + N_V;         // 5000
  int* ctr = deg_a + N_A;           // 4
  float* hacc = (float*)(ctr + 4);              // N_V*32 (becomes fv in-place)
  float* hacc_a = hacc + (size_t)N_V * EMB;     // N_A*32
  int* off_g = (int*)(hacc_a + (size_t)N_A * EMB);  // 100000
  int* off_h = off_g + N_V;                         // 100000
  int* off_a = off_h + N_V;                         // 5000
  u64* P = (u64*)(off_a + N_A);

  const size_t base_bytes = (size_t)3770004 * 4;
  const size_t rank_bytes = (size_t)E_C2V + E_A2V + 2 * E_A2V;
  const size_t need_big = base_bytes + (size_t)3600000 * 8 + rank_bytes;
  bool big = ws_size >= need_big;

  u64* pay_g = P;
  u64* pay_h = big ? (P + E_C2V) : P;
  u64* pay_a = big ? (P + E_C2V + E_A2V) : (P + E_A2V);
  size_t p_total = big ? 3600000 : 2000000;
  u8* rank_g = (u8*)(P + p_total);
  u8* rank_h = rank_g + E_C2V;
  unsigned short* rank_a = (unsigned short*)(rank_h + E_A2V);

  hipMemsetAsync(d_ws, 0,
                 (size_t)205004 * sizeof(int) +
                     (size_t)(N_V + N_A) * EMB * sizeof(float),
                 stream);

  // merged counts: rank_a histogram blocks first (start at t=0, hide
  // under the 6250-block g/h atomic stream)
  k_counts_all<<<NRA + NCH, 256, 0, stream>>>(
      c2v_t, a2v_t, a2v_s, deg_g, deg_h, deg_a, rank_g, rank_h, rank_a);
  k_allocs<<<2 * NBV + NBA, 256, 0, stream>>>(deg_g, off_g, deg_h, off_h,
                                              deg_a, off_a, ctr);
  if (big) {
    k_fill_all<<<8 * NCH + 8 * NCHA, 256, 0, stream>>>(
        c2v_t, c2v_s, ea_c2v, a2v_t, a2v_s, ea_a2v,
        off_g, rank_g, pay_g, off_h, rank_h, pay_h, off_a, rank_a, pay_a);
    k_edge_v<0><<<E_C2V / 256, 256, 0, stream>>>(
        E_C2V, pay_g, x_v, x_c, gv_W1, gv_b1, gv_W2, gv_b2,
        fv_W1 + (size_t)D_V * EMB, deg_g, hacc);
  } else {
    k_fill_g<<<8 * NCH, 256, 0, stream>>>(c2v_t, c2v_s, ea_c2v, off_g, rank_g,
                                          pay_g);
    k_edge_v<0><<<E_C2V / 256, 256, 0, stream>>>(
        E_C2V, pay_g, x_v, x_c, gv_W1, gv_b1, gv_W2, gv_b2,
        fv_W1 + (size_t)D_V * EMB, deg_g, hacc);
    k_fill_ha<<<8 * NCHA, 256, 0, stream>>>(a2v_t, a2v_s, ea_a2v,
                                            off_h, rank_h, pay_h,
                                            off_a, rank_a, pay_a);
  }
  k_edge_v<1><<<NCHA, 256, 0, stream>>>(
      E_A2V, pay_h, x_v, x_a, hv_W1, hv_b1, hv_W2, hv_b2,
      fv_W1 + (size_t)(D_V + EMB) * EMB, deg_h, hacc);
  // f_v in-place: hacc rows become fv rows
  k_node_fv<<<(N_V + 255) / 256, 256, 0, stream>>>(
      x_v, hacc, fv_W1, fv_b1, fv_W2, fv_b2);
  // a side edge MLP + reduce -> hacc_a
  k_edge_a<<<NCHA, 256, 0, stream>>>(
      pay_a, x_a, hacc, ga_W1, ga_b1, ga_W2, ga_b2,
      fa_W1 + (size_t)D_A * EMB, deg_a, hacc_a);
  // f_a -> out
  k_node_fa<<<(N_A + 255) / 256, 256, 0, stream>>>(
      x_a, hacc_a, fa_W1, fa_b1, fa_W2, fa_b2, (float*)d_out);
}